// Round 1
// baseline (19222.687 us; speedup 1.0000x reference)
//
#include <hip/hip_runtime.h>
#include <math.h>

// Problem constants (match reference)
constexpr int kB = 2, kS = 2048, kD = 1024, kH = 16, kF = 4096, kL = 3;
constexpr int kDK = 64;

// ---------------------------------------------------------------------------
// Embedding: x[b,s,:] = emb[tok]*sqrt(D) + pe[s,:]
// grid = B*S blocks of 256; each thread handles one float4 (D=1024 = 256*4)
// ---------------------------------------------------------------------------
__global__ __launch_bounds__(256) void embed_kernel(
    const int* __restrict__ tokens, const float* __restrict__ emb,
    const float* __restrict__ pe, float* __restrict__ x)
{
  int i = blockIdx.x;            // b*kS + s
  int s = i & (kS - 1);
  int tok = tokens[i];
  const float4* ep = (const float4*)(emb + (size_t)tok * kD);
  const float4* pp = (const float4*)(pe + (size_t)s * kD);
  float4* xp = (float4*)(x + (size_t)i * kD);
  int t = threadIdx.x;
  float4 e = ep[t], p = pp[t];
  xp[t] = make_float4(e.x*32.0f + p.x, e.y*32.0f + p.y,
                      e.z*32.0f + p.z, e.w*32.0f + p.w);
}

// ---------------------------------------------------------------------------
// LayerNorm, torch-style: std is Bessel-corrected (ddof=1), eps added to std.
// One block (256 thr) per row of 1024. Each thread owns one float4.
// ---------------------------------------------------------------------------
__global__ __launch_bounds__(256) void ln_kernel(
    const float* __restrict__ x, const float* __restrict__ ga,
    const float* __restrict__ gb, float* __restrict__ out)
{
  int row = blockIdx.x;
  int t = threadIdx.x;
  int lane = t & 63, wid = t >> 6;
  const float4* xp = (const float4*)(x + (size_t)row * kD);
  float4 v = xp[t];
  float s = v.x + v.y + v.z + v.w;
  #pragma unroll
  for (int o = 32; o; o >>= 1) s += __shfl_xor(s, o);
  __shared__ float red[4];
  if (lane == 0) red[wid] = s;
  __syncthreads();
  float mean = (red[0] + red[1] + red[2] + red[3]) * (1.0f / 1024.0f);
  float4 d = make_float4(v.x - mean, v.y - mean, v.z - mean, v.w - mean);
  float ss = d.x*d.x + d.y*d.y + d.z*d.z + d.w*d.w;
  #pragma unroll
  for (int o = 32; o; o >>= 1) ss += __shfl_xor(ss, o);
  __syncthreads();
  if (lane == 0) red[wid] = ss;
  __syncthreads();
  float var = (red[0] + red[1] + red[2] + red[3]) * (1.0f / 1023.0f);
  float inv = 1.0f / (sqrtf(var) + 1e-6f);
  float4 a4 = ((const float4*)ga)[t];
  float4 b4 = ((const float4*)gb)[t];
  float4 o4;
  o4.x = a4.x * d.x * inv + b4.x;
  o4.y = a4.y * d.y * inv + b4.y;
  o4.z = a4.z * d.z * inv + b4.z;
  o4.w = a4.w * d.w * inv + b4.w;
  ((float4*)(out + (size_t)row * kD))[t] = o4;
}

// ---------------------------------------------------------------------------
// SGEMM: out[M,N] = A[M,K] @ W[K,N] + bias[N]  (+ resid[M,N]) (optional relu)
// BM=BN=128, BK=16, 256 threads, 8x8 micro-tile split as {4ty,64+4ty}x{4tx,64+4tx}
// (split keeps LDS reads at 2-way bank aliasing = free on gfx950)
// ---------------------------------------------------------------------------
#define GBM 128
#define GBN 128
#define GBK 16

__global__ __launch_bounds__(256) void gemm_kernel(
    const float* __restrict__ A, const float* __restrict__ W,
    const float* __restrict__ bias, const float* __restrict__ resid,
    float* __restrict__ out, int M, int N, int K, int relu)
{
  __shared__ float As[GBK][GBM + 4];   // [k][m], +4 pad keeps 16B align, kills conflicts
  __shared__ float Bs[GBK][GBN];       // [k][n]
  int t = threadIdx.x;
  int tx = t & 15, ty = t >> 4;
  int m0 = blockIdx.y * GBM, n0 = blockIdx.x * GBN;

  float acc[8][8];
  #pragma unroll
  for (int i = 0; i < 8; ++i)
    #pragma unroll
    for (int j = 0; j < 8; ++j) acc[i][j] = 0.0f;

  for (int k0 = 0; k0 < K; k0 += GBK) {
    // A tile 128x16 = 512 float4 loads (2/thread), scatter to As[k][m]
    #pragma unroll
    for (int l = 0; l < 2; ++l) {
      int idx = t + 256 * l;
      int row = idx >> 2, c4 = idx & 3;
      float4 a = *(const float4*)&A[(size_t)(m0 + row) * K + k0 + 4 * c4];
      As[4*c4 + 0][row] = a.x;
      As[4*c4 + 1][row] = a.y;
      As[4*c4 + 2][row] = a.z;
      As[4*c4 + 3][row] = a.w;
    }
    // B tile 16x128 = 512 float4 loads (2/thread), contiguous
    #pragma unroll
    for (int l = 0; l < 2; ++l) {
      int idx = t + 256 * l;
      int kr = idx >> 5, c4 = idx & 31;
      *(float4*)&Bs[kr][4 * c4] =
          *(const float4*)&W[(size_t)(k0 + kr) * N + n0 + 4 * c4];
    }
    __syncthreads();
    #pragma unroll
    for (int kk = 0; kk < GBK; ++kk) {
      float4 a0 = *(const float4*)&As[kk][4 * ty];
      float4 a1 = *(const float4*)&As[kk][64 + 4 * ty];
      float4 b0 = *(const float4*)&Bs[kk][4 * tx];
      float4 b1 = *(const float4*)&Bs[kk][64 + 4 * tx];
      float av[8] = {a0.x, a0.y, a0.z, a0.w, a1.x, a1.y, a1.z, a1.w};
      float bv[8] = {b0.x, b0.y, b0.z, b0.w, b1.x, b1.y, b1.z, b1.w};
      #pragma unroll
      for (int i = 0; i < 8; ++i)
        #pragma unroll
        for (int j = 0; j < 8; ++j) acc[i][j] += av[i] * bv[j];
    }
    __syncthreads();
  }

  // epilogue: bias (+resid) (+relu), two float4 stores per micro-row
  #pragma unroll
  for (int i = 0; i < 8; ++i) {
    int row = m0 + ((i < 4) ? (4 * ty + i) : (64 + 4 * ty + (i - 4)));
    #pragma unroll
    for (int jh = 0; jh < 2; ++jh) {
      int col = n0 + ((jh == 0) ? (4 * tx) : (64 + 4 * tx));
      float4 r = make_float4(acc[i][4*jh+0], acc[i][4*jh+1],
                             acc[i][4*jh+2], acc[i][4*jh+3]);
      float4 bv = *(const float4*)&bias[col];
      r.x += bv.x; r.y += bv.y; r.z += bv.z; r.w += bv.w;
      if (resid) {
        float4 rv = *(const float4*)&resid[(size_t)row * N + col];
        r.x += rv.x; r.y += rv.y; r.z += rv.z; r.w += rv.w;
      }
      if (relu) {
        r.x = fmaxf(r.x, 0.0f); r.y = fmaxf(r.y, 0.0f);
        r.z = fmaxf(r.z, 0.0f); r.w = fmaxf(r.w, 0.0f);
      }
      *(float4*)&out[(size_t)row * N + col] = r;
    }
  }
}

// ---------------------------------------------------------------------------
// Fused attention: one block per (b, h, 4 query rows).
// Scores live entirely in LDS (32KB) — never materialized in HBM.
// q is pre-scaled by 1/sqrt(DK); mask==0 -> -1e9 (exact reference semantics).
// Softmax: one wave per query row, shuffle reduce. PV: coalesced V reads.
// ---------------------------------------------------------------------------
__global__ __launch_bounds__(256) void attn_kernel(
    const float* __restrict__ Q, const float* __restrict__ K,
    const float* __restrict__ V, const int* __restrict__ mask,
    float* __restrict__ O)
{
  int bi = blockIdx.x;
  int q4 = bi & (kS / 4 - 1);          // 512
  int h  = (bi >> 9) & (kH - 1);
  int b  = bi >> 13;
  int q0 = q4 * 4;
  int t = threadIdx.x;
  int lane = t & 63, wid = t >> 6;

  __shared__ float qs[4][64];
  __shared__ float sc[4][kS];          // 32 KB
  __shared__ float opart[4][4][64];
  __shared__ float invsum[4];

  {
    int r = t >> 6, d = t & 63;
    qs[r][d] = Q[(size_t)(b * kS + q0 + r) * kD + h * kDK + d] * 0.125f;
  }
  __syncthreads();

  // ---- scores: each thread owns 8 keys (j = t + 256i), all 4 rows ----
  float accS[8][4];
  #pragma unroll
  for (int i = 0; i < 8; ++i)
    #pragma unroll
    for (int r = 0; r < 4; ++r) accS[i][r] = 0.0f;

  const size_t kbase = (size_t)b * kS * kD + (size_t)h * kDK;
  #pragma unroll
  for (int c = 0; c < 8; ++c) {        // d-chunks of 8: q kept in registers
    float4 q0r[4], q1r[4];
    #pragma unroll
    for (int r = 0; r < 4; ++r) {
      q0r[r] = *(const float4*)&qs[r][8 * c];
      q1r[r] = *(const float4*)&qs[r][8 * c + 4];
    }
    #pragma unroll
    for (int i = 0; i < 8; ++i) {
      int j = t + 256 * i;
      const float4* kp = (const float4*)(K + kbase + (size_t)j * kD);
      float4 k0v = kp[2 * c], k1v = kp[2 * c + 1];
      #pragma unroll
      for (int r = 0; r < 4; ++r) {
        accS[i][r] += q0r[r].x*k0v.x + q0r[r].y*k0v.y + q0r[r].z*k0v.z + q0r[r].w*k0v.w
                    + q1r[r].x*k1v.x + q1r[r].y*k1v.y + q1r[r].z*k1v.z + q1r[r].w*k1v.w;
      }
    }
  }
  #pragma unroll
  for (int i = 0; i < 8; ++i) {
    int j = t + 256 * i;
    int mv = mask[b * kS + j];
    #pragma unroll
    for (int r = 0; r < 4; ++r)
      sc[r][j] = mv ? accS[i][r] : -1e9f;
  }
  __syncthreads();

  // ---- softmax: wave `wid` handles row `wid` ----
  {
    int r = wid;
    float mx = -3.0e38f;
    #pragma unroll 8
    for (int i = 0; i < 32; ++i) mx = fmaxf(mx, sc[r][lane + 64 * i]);
    #pragma unroll
    for (int o = 32; o; o >>= 1) mx = fmaxf(mx, __shfl_xor(mx, o));
    float sum = 0.0f;
    #pragma unroll 8
    for (int i = 0; i < 32; ++i) {
      float e = __expf(sc[r][lane + 64 * i] - mx);
      sc[r][lane + 64 * i] = e;
      sum += e;
    }
    #pragma unroll
    for (int o = 32; o; o >>= 1) sum += __shfl_xor(sum, o);
    if (lane == 0) invsum[r] = 1.0f / sum;
  }
  __syncthreads();

  // ---- PV: wave g takes keys j ≡ g (mod 4); lane = output dim (coalesced V) ----
  {
    int g = wid, d = lane;
    float a0 = 0, a1 = 0, a2 = 0, a3 = 0;
    const float* vb = V + (size_t)b * kS * kD + (size_t)h * kDK + d;
    #pragma unroll 8
    for (int j = g; j < kS; j += 4) {
      float vv = vb[(size_t)j * kD];
      a0 += sc[0][j] * vv; a1 += sc[1][j] * vv;
      a2 += sc[2][j] * vv; a3 += sc[3][j] * vv;
    }
    opart[g][0][d] = a0; opart[g][1][d] = a1;
    opart[g][2][d] = a2; opart[g][3][d] = a3;
  }
  __syncthreads();
  {
    int r = wid, d = lane;
    float o = (opart[0][r][d] + opart[1][r][d] +
               opart[2][r][d] + opart[3][r][d]) * invsum[r];
    O[(size_t)(b * kS + q0 + r) * kD + (size_t)h * kDK + d] = o;
  }
}

// ---------------------------------------------------------------------------
// Orchestration. Workspace layout (floats), TD = B*S*D = 4M:
//   x: [0, TD)   h/o: [TD, 2TD)   q: [2TD,3TD)  k: [3TD,4TD)  v: [4TD,5TD)
//   f: [2TD, 2TD + B*S*F)  -- aliases q,k,v after attention (they're dead)
// Total: 2TD + 16M floats = 100.7 MB.
// ---------------------------------------------------------------------------
extern "C" void kernel_launch(void* const* d_in, const int* in_sizes, int n_in,
                              void* d_out, int out_size, void* d_ws, size_t ws_size,
                              hipStream_t stream) {
  const int*   tokens = (const int*)d_in[0];
  const int*   mask   = (const int*)d_in[1];
  const float* emb    = (const float*)d_in[2];
  const float* pe     = (const float*)d_in[3];
  const float* Wq     = (const float*)d_in[4];
  const float* bq     = (const float*)d_in[5];
  const float* Wk     = (const float*)d_in[6];
  const float* bk     = (const float*)d_in[7];
  const float* Wv     = (const float*)d_in[8];
  const float* bv     = (const float*)d_in[9];
  const float* Wo     = (const float*)d_in[10];
  const float* bo     = (const float*)d_in[11];
  const float* w1     = (const float*)d_in[12];
  const float* b1     = (const float*)d_in[13];
  const float* w2     = (const float*)d_in[14];
  const float* b2     = (const float*)d_in[15];
  const float* ln_a   = (const float*)d_in[16];
  const float* ln_b   = (const float*)d_in[17];
  const float* fa     = (const float*)d_in[18];
  const float* fb     = (const float*)d_in[19];
  float* out = (float*)d_out;
  float* ws  = (float*)d_ws;

  const int T = kB * kS;               // 4096 rows
  const size_t TD = (size_t)T * kD;    // 4M floats
  float* x = ws;
  float* h = ws + TD;
  float* q = ws + 2 * TD;
  float* k = ws + 3 * TD;
  float* v = ws + 4 * TD;
  float* f = ws + 2 * TD;              // aliases q,k,v (dead by FFN time)

  dim3 blk(256);
  embed_kernel<<<T, blk, 0, stream>>>(tokens, emb, pe, x);

  for (int l = 0; l < kL; ++l) {
    const float* Wql = Wq + (size_t)l * kD * kD;
    const float* Wkl = Wk + (size_t)l * kD * kD;
    const float* Wvl = Wv + (size_t)l * kD * kD;
    const float* Wol = Wo + (size_t)l * kD * kD;
    const float* w1l = w1 + (size_t)l * kD * kF;
    const float* w2l = w2 + (size_t)l * kF * kD;

    // --- attention sublayer ---
    ln_kernel<<<T, blk, 0, stream>>>(x, ln_a + (size_t)l * 2 * kD,
                                     ln_b + (size_t)l * 2 * kD, h);
    gemm_kernel<<<dim3(kD / GBN, T / GBM), blk, 0, stream>>>(
        h, Wql, bq + (size_t)l * kD, nullptr, q, T, kD, kD, 0);
    gemm_kernel<<<dim3(kD / GBN, T / GBM), blk, 0, stream>>>(
        h, Wkl, bk + (size_t)l * kD, nullptr, k, T, kD, kD, 0);
    gemm_kernel<<<dim3(kD / GBN, T / GBM), blk, 0, stream>>>(
        h, Wvl, bv + (size_t)l * kD, nullptr, v, T, kD, kD, 0);
    attn_kernel<<<kB * kH * (kS / 4), blk, 0, stream>>>(q, k, v, mask, h);
    gemm_kernel<<<dim3(kD / GBN, T / GBM), blk, 0, stream>>>(
        h, Wol, bo + (size_t)l * kD, x, x, T, kD, kD, 0);

    // --- feed-forward sublayer ---
    ln_kernel<<<T, blk, 0, stream>>>(x, ln_a + (size_t)l * 2 * kD + kD,
                                     ln_b + (size_t)l * 2 * kD + kD, h);
    gemm_kernel<<<dim3(kF / GBN, T / GBM), blk, 0, stream>>>(
        h, w1l, b1 + (size_t)l * kF, nullptr, f, T, kF, kD, 1);
    gemm_kernel<<<dim3(kD / GBN, T / GBM), blk, 0, stream>>>(
        f, w2l, b2 + (size_t)l * kD, x, x, T, kD, kF, 0);
  }

  ln_kernel<<<T, blk, 0, stream>>>(x, fa, fb, out);
}

// Round 2
// 11215.330 us; speedup vs baseline: 1.7140x; 1.7140x over previous
//
#include <hip/hip_runtime.h>
#include <math.h>

// Problem constants (match reference)
constexpr int kB = 2, kS = 2048, kD = 1024, kH = 16, kF = 4096, kL = 3;
constexpr int kDK = 64;

// ---------------------------------------------------------------------------
// Embedding: x[b,s,:] = emb[tok]*sqrt(D) + pe[s,:]
// ---------------------------------------------------------------------------
__global__ __launch_bounds__(256) void embed_kernel(
    const int* __restrict__ tokens, const float* __restrict__ emb,
    const float* __restrict__ pe, float* __restrict__ x)
{
  int i = blockIdx.x;            // b*kS + s
  int s = i & (kS - 1);
  int tok = tokens[i];
  const float4* ep = (const float4*)(emb + (size_t)tok * kD);
  const float4* pp = (const float4*)(pe + (size_t)s * kD);
  float4* xp = (float4*)(x + (size_t)i * kD);
  int t = threadIdx.x;
  float4 e = ep[t], p = pp[t];
  xp[t] = make_float4(e.x*32.0f + p.x, e.y*32.0f + p.y,
                      e.z*32.0f + p.z, e.w*32.0f + p.w);
}

// ---------------------------------------------------------------------------
// LayerNorm, torch-style: Bessel-corrected std (ddof=1), eps added to std.
// ---------------------------------------------------------------------------
__global__ __launch_bounds__(256) void ln_kernel(
    const float* __restrict__ x, const float* __restrict__ ga,
    const float* __restrict__ gb, float* __restrict__ out)
{
  int row = blockIdx.x;
  int t = threadIdx.x;
  int lane = t & 63, wid = t >> 6;
  const float4* xp = (const float4*)(x + (size_t)row * kD);
  float4 v = xp[t];
  float s = v.x + v.y + v.z + v.w;
  #pragma unroll
  for (int o = 32; o; o >>= 1) s += __shfl_xor(s, o);
  __shared__ float red[4];
  if (lane == 0) red[wid] = s;
  __syncthreads();
  float mean = (red[0] + red[1] + red[2] + red[3]) * (1.0f / 1024.0f);
  float4 d = make_float4(v.x - mean, v.y - mean, v.z - mean, v.w - mean);
  float ss = d.x*d.x + d.y*d.y + d.z*d.z + d.w*d.w;
  #pragma unroll
  for (int o = 32; o; o >>= 1) ss += __shfl_xor(ss, o);
  __syncthreads();
  if (lane == 0) red[wid] = ss;
  __syncthreads();
  float var = (red[0] + red[1] + red[2] + red[3]) * (1.0f / 1023.0f);
  float inv = 1.0f / (sqrtf(var) + 1e-6f);
  float4 a4 = ((const float4*)ga)[t];
  float4 b4 = ((const float4*)gb)[t];
  float4 o4;
  o4.x = a4.x * d.x * inv + b4.x;
  o4.y = a4.y * d.y * inv + b4.y;
  o4.z = a4.z * d.z * inv + b4.z;
  o4.w = a4.w * d.w * inv + b4.w;
  ((float4*)(out + (size_t)row * kD))[t] = o4;
}

// ---------------------------------------------------------------------------
// SGEMM: out[M,N] = A[M,K] @ W[K,N] + bias[N]  (+ resid[M,N]) (optional relu)
// BM=BN=128, BK=16, 256 threads, 8x8 micro-tile (16 FMA per ds_read_b128 —
// balanced against the 128 B/cyc LDS pipe). ~75 TF measured in R0.
// ---------------------------------------------------------------------------
#define GBM 128
#define GBN 128
#define GBK 16

__global__ __launch_bounds__(256) void gemm_kernel(
    const float* __restrict__ A, const float* __restrict__ W,
    const float* __restrict__ bias, const float* __restrict__ resid,
    float* __restrict__ out, int M, int N, int K, int relu)
{
  __shared__ float As[GBK][GBM + 4];
  __shared__ float Bs[GBK][GBN];
  int t = threadIdx.x;
  int tx = t & 15, ty = t >> 4;
  int m0 = blockIdx.y * GBM, n0 = blockIdx.x * GBN;

  float acc[8][8];
  #pragma unroll
  for (int i = 0; i < 8; ++i)
    #pragma unroll
    for (int j = 0; j < 8; ++j) acc[i][j] = 0.0f;

  for (int k0 = 0; k0 < K; k0 += GBK) {
    #pragma unroll
    for (int l = 0; l < 2; ++l) {
      int idx = t + 256 * l;
      int row = idx >> 2, c4 = idx & 3;
      float4 a = *(const float4*)&A[(size_t)(m0 + row) * K + k0 + 4 * c4];
      As[4*c4 + 0][row] = a.x;
      As[4*c4 + 1][row] = a.y;
      As[4*c4 + 2][row] = a.z;
      As[4*c4 + 3][row] = a.w;
    }
    #pragma unroll
    for (int l = 0; l < 2; ++l) {
      int idx = t + 256 * l;
      int kr = idx >> 5, c4 = idx & 31;
      *(float4*)&Bs[kr][4 * c4] =
          *(const float4*)&W[(size_t)(k0 + kr) * N + n0 + 4 * c4];
    }
    __syncthreads();
    #pragma unroll
    for (int kk = 0; kk < GBK; ++kk) {
      float4 a0 = *(const float4*)&As[kk][4 * ty];
      float4 a1 = *(const float4*)&As[kk][64 + 4 * ty];
      float4 b0 = *(const float4*)&Bs[kk][4 * tx];
      float4 b1 = *(const float4*)&Bs[kk][64 + 4 * tx];
      float av[8] = {a0.x, a0.y, a0.z, a0.w, a1.x, a1.y, a1.z, a1.w};
      float bv[8] = {b0.x, b0.y, b0.z, b0.w, b1.x, b1.y, b1.z, b1.w};
      #pragma unroll
      for (int i = 0; i < 8; ++i)
        #pragma unroll
        for (int j = 0; j < 8; ++j) acc[i][j] += av[i] * bv[j];
    }
    __syncthreads();
  }

  #pragma unroll
  for (int i = 0; i < 8; ++i) {
    int row = m0 + ((i < 4) ? (4 * ty + i) : (64 + 4 * ty + (i - 4)));
    #pragma unroll
    for (int jh = 0; jh < 2; ++jh) {
      int col = n0 + ((jh == 0) ? (4 * tx) : (64 + 4 * tx));
      float4 r = make_float4(acc[i][4*jh+0], acc[i][4*jh+1],
                             acc[i][4*jh+2], acc[i][4*jh+3]);
      float4 bv = *(const float4*)&bias[col];
      r.x += bv.x; r.y += bv.y; r.z += bv.z; r.w += bv.w;
      if (resid) {
        float4 rv = *(const float4*)&resid[(size_t)row * N + col];
        r.x += rv.x; r.y += rv.y; r.z += rv.z; r.w += rv.w;
      }
      if (relu) {
        r.x = fmaxf(r.x, 0.0f); r.y = fmaxf(r.y, 0.0f);
        r.z = fmaxf(r.z, 0.0f); r.w = fmaxf(r.w, 0.0f);
      }
      *(float4*)&out[(size_t)row * N + col] = r;
    }
  }
}

// ---------------------------------------------------------------------------
// Flash-style fused attention. One block = (b, h, 64-query tile), 256 thr.
// K/V staged through LDS in 64-key chunks; online softmax (m,l per row);
// P round-trips through LDS so every thread sums over ALL chunk keys (no
// cross-thread O reduction). All 64x64 buffers XOR-swizzled: float4 chunk c
// of row r lives at 4*(c ^ (r&15)) -> every ds_read_b128 hits the 2-phase
// floor (16 distinct rows x 16B = 256B @ 128B/cyc). Static LDS = 64 KB
// exactly; __launch_bounds__(256,2) caps VGPR<=128 -> 2 blocks/CU.
// Register budget: sacc 16 + Oacc 16 + m/l 8 + frags 32 + addr ~25 ≈ 100.
// ---------------------------------------------------------------------------
__global__ __launch_bounds__(256, 2) void attn_kernel(
    const float* __restrict__ Q, const float* __restrict__ K,
    const float* __restrict__ V, const int* __restrict__ mask,
    float* __restrict__ O)
{
  __shared__ float Qs[64 * 64];
  __shared__ float Ks[64 * 64];
  __shared__ float Vs[64 * 64];
  __shared__ float Ps[64 * 64];

  int bi = blockIdx.x;
  int qt = bi & 31;              // S/64 = 32 q-tiles
  int h  = (bi >> 5) & 15;
  int b  = bi >> 9;
  int q0 = qt * 64;
  int t  = threadIdx.x;
  int tk = t & 15, tq = t >> 4;  // rows owned: tq+16i; cols owned: tk+16j

  const size_t hbase = (size_t)b * kS * kD + (size_t)h * kDK;

  // stage Q once (pre-scaled by 1/sqrt(DK)=0.125), swizzled
  #pragma unroll
  for (int p = 0; p < 4; ++p) {
    int idx = t + 256 * p;
    int row = idx >> 4, c = idx & 15;
    float4 qv = *(const float4*)&Q[hbase + (size_t)(q0 + row) * kD + 4 * c];
    qv.x *= 0.125f; qv.y *= 0.125f; qv.z *= 0.125f; qv.w *= 0.125f;
    *(float4*)&Qs[row * 64 + 4 * (c ^ (row & 15))] = qv;
  }

  float Oacc[4][4];
  float m_i[4], l_i[4];
  #pragma unroll
  for (int i = 0; i < 4; ++i) {
    m_i[i] = -1e30f; l_i[i] = 0.0f;
    #pragma unroll
    for (int d = 0; d < 4; ++d) Oacc[i][d] = 0.0f;
  }

  for (int k0 = 0; k0 < kS; k0 += 64) {
    __syncthreads();   // prev chunk's Ks/Vs/Ps readers done (covers Qs on iter 0)

    // stage K,V chunk (coalesced 64B row-segments), swizzled
    #pragma unroll
    for (int p = 0; p < 4; ++p) {
      int idx = t + 256 * p;
      int row = idx >> 4, c = idx & 15;
      size_t g = hbase + (size_t)(k0 + row) * kD + 4 * c;
      int lo = row * 64 + 4 * (c ^ (row & 15));
      *(float4*)&Ks[lo] = *(const float4*)&K[g];
      *(float4*)&Vs[lo] = *(const float4*)&V[g];
    }
    __syncthreads();

    // ---- S = Q K^T : 4q x 4k micro-tile, dot over 64 dims ----
    float sacc[4][4] = {};
    #pragma unroll
    for (int dc = 0; dc < 16; ++dc) {
      float4 qf[4], kf[4];
      #pragma unroll
      for (int i = 0; i < 4; ++i)
        qf[i] = *(const float4*)&Qs[(tq + 16*i) * 64 + 4 * (dc ^ tq)];
      #pragma unroll
      for (int j = 0; j < 4; ++j)
        kf[j] = *(const float4*)&Ks[(tk + 16*j) * 64 + 4 * (dc ^ tk)];
      #pragma unroll
      for (int i = 0; i < 4; ++i)
        #pragma unroll
        for (int j = 0; j < 4; ++j)
          sacc[i][j] += qf[i].x*kf[j].x + qf[i].y*kf[j].y
                      + qf[i].z*kf[j].z + qf[i].w*kf[j].w;
    }

    // mask (reference: where mask==0 -> -1e9 BEFORE softmax)
    #pragma unroll
    for (int j = 0; j < 4; ++j) {
      if (mask[b * kS + k0 + tk + 16*j] == 0) {
        #pragma unroll
        for (int i = 0; i < 4; ++i) sacc[i][j] = -1e9f;
      }
    }

    // ---- online softmax: row owners are the 16 tk-lanes (same wave) ----
    #pragma unroll
    for (int i = 0; i < 4; ++i) {
      float mx = fmaxf(fmaxf(sacc[i][0], sacc[i][1]),
                       fmaxf(sacc[i][2], sacc[i][3]));
      #pragma unroll
      for (int o = 8; o; o >>= 1) mx = fmaxf(mx, __shfl_xor(mx, o));
      float newm = fmaxf(m_i[i], mx);
      float alpha = __expf(m_i[i] - newm);
      float rs = 0.0f;
      #pragma unroll
      for (int j = 0; j < 4; ++j) {
        float pv = __expf(sacc[i][j] - newm);
        sacc[i][j] = pv; rs += pv;
      }
      #pragma unroll
      for (int o = 8; o; o >>= 1) rs += __shfl_xor(rs, o);
      l_i[i] = l_i[i] * alpha + rs;
      m_i[i] = newm;
      #pragma unroll
      for (int d = 0; d < 4; ++d) Oacc[i][d] *= alpha;
    }

    // write P to LDS (swizzled scalar stores)
    #pragma unroll
    for (int i = 0; i < 4; ++i)
      #pragma unroll
      for (int j = 0; j < 4; ++j) {
        int col = tk + 16*j;
        Ps[(tq + 16*i) * 64 + 4 * ((col >> 2) ^ tq) + (col & 3)] = sacc[i][j];
      }
    __syncthreads();

    // ---- O += P V : 4q x 4d micro-tile over the 64 chunk keys ----
    #pragma unroll
    for (int kc = 0; kc < 16; ++kc) {
      float4 pf[4], vf[4];
      #pragma unroll
      for (int i = 0; i < 4; ++i)
        pf[i] = *(const float4*)&Ps[(tq + 16*i) * 64 + 4 * (kc ^ tq)];
      #pragma unroll
      for (int r = 0; r < 4; ++r)
        vf[r] = *(const float4*)&Vs[(4*kc + r) * 64 + 4 * (tk ^ ((4*kc + r) & 15))];
      #pragma unroll
      for (int i = 0; i < 4; ++i) {
        Oacc[i][0] += pf[i].x*vf[0].x + pf[i].y*vf[1].x + pf[i].z*vf[2].x + pf[i].w*vf[3].x;
        Oacc[i][1] += pf[i].x*vf[0].y + pf[i].y*vf[1].y + pf[i].z*vf[2].y + pf[i].w*vf[3].y;
        Oacc[i][2] += pf[i].x*vf[0].z + pf[i].y*vf[1].z + pf[i].z*vf[2].z + pf[i].w*vf[3].z;
        Oacc[i][3] += pf[i].x*vf[0].w + pf[i].y*vf[1].w + pf[i].z*vf[2].w + pf[i].w*vf[3].w;
      }
    }
  }

  // epilogue: O = Oacc / l   (coalesced 256B segments per row)
  #pragma unroll
  for (int i = 0; i < 4; ++i) {
    float inv = 1.0f / l_i[i];
    float4 o = make_float4(Oacc[i][0]*inv, Oacc[i][1]*inv,
                           Oacc[i][2]*inv, Oacc[i][3]*inv);
    *(float4*)&O[hbase + (size_t)(q0 + tq + 16*i) * kD + 4*tk] = o;
  }
}

// ---------------------------------------------------------------------------
// Orchestration. Workspace (floats), TD = B*S*D = 4M:
//   x:[0,TD)  h:[TD,2TD)  q:[2TD,3TD)  k:[3TD,4TD)  v:[4TD,5TD)
//   f:[2TD, 2TD+B*S*F)  aliases q,k,v (dead by FFN time). Total 100.7 MB.
// ---------------------------------------------------------------------------
extern "C" void kernel_launch(void* const* d_in, const int* in_sizes, int n_in,
                              void* d_out, int out_size, void* d_ws, size_t ws_size,
                              hipStream_t stream) {
  const int*   tokens = (const int*)d_in[0];
  const int*   mask   = (const int*)d_in[1];
  const float* emb    = (const float*)d_in[2];
  const float* pe     = (const float*)d_in[3];
  const float* Wq     = (const float*)d_in[4];
  const float* bq     = (const float*)d_in[5];
  const float* Wk     = (const float*)d_in[6];
  const float* bk     = (const float*)d_in[7];
  const float* Wv     = (const float*)d_in[8];
  const float* bv     = (const float*)d_in[9];
  const float* Wo     = (const float*)d_in[10];
  const float* bo     = (const float*)d_in[11];
  const float* w1     = (const float*)d_in[12];
  const float* b1     = (const float*)d_in[13];
  const float* w2     = (const float*)d_in[14];
  const float* b2     = (const float*)d_in[15];
  const float* ln_a   = (const float*)d_in[16];
  const float* ln_b   = (const float*)d_in[17];
  const float* fa     = (const float*)d_in[18];
  const float* fb     = (const float*)d_in[19];
  float* out = (float*)d_out;
  float* ws  = (float*)d_ws;

  const int T = kB * kS;               // 4096 rows
  const size_t TD = (size_t)T * kD;
  float* x = ws;
  float* h = ws + TD;
  float* q = ws + 2 * TD;
  float* k = ws + 3 * TD;
  float* v = ws + 4 * TD;
  float* f = ws + 2 * TD;              // aliases q,k,v

  dim3 blk(256);
  embed_kernel<<<T, blk, 0, stream>>>(tokens, emb, pe, x);

  for (int l = 0; l < kL; ++l) {
    const float* Wql = Wq + (size_t)l * kD * kD;
    const float* Wkl = Wk + (size_t)l * kD * kD;
    const float* Wvl = Wv + (size_t)l * kD * kD;
    const float* Wol = Wo + (size_t)l * kD * kD;
    const float* w1l = w1 + (size_t)l * kD * kF;
    const float* w2l = w2 + (size_t)l * kF * kD;

    // --- attention sublayer ---
    ln_kernel<<<T, blk, 0, stream>>>(x, ln_a + (size_t)l * 2 * kD,
                                     ln_b + (size_t)l * 2 * kD, h);
    gemm_kernel<<<dim3(kD / GBN, T / GBM), blk, 0, stream>>>(
        h, Wql, bq + (size_t)l * kD, nullptr, q, T, kD, kD, 0);
    gemm_kernel<<<dim3(kD / GBN, T / GBM), blk, 0, stream>>>(
        h, Wkl, bk + (size_t)l * kD, nullptr, k, T, kD, kD, 0);
    gemm_kernel<<<dim3(kD / GBN, T / GBM), blk, 0, stream>>>(
        h, Wvl, bv + (size_t)l * kD, nullptr, v, T, kD, kD, 0);
    attn_kernel<<<kB * kH * (kS / 64), blk, 0, stream>>>(q, k, v, mask, h);
    gemm_kernel<<<dim3(kD / GBN, T / GBM), blk, 0, stream>>>(
        h, Wol, bo + (size_t)l * kD, x, x, T, kD, kD, 0);

    // --- feed-forward sublayer ---
    ln_kernel<<<T, blk, 0, stream>>>(x, ln_a + (size_t)l * 2 * kD + kD,
                                     ln_b + (size_t)l * 2 * kD + kD, h);
    gemm_kernel<<<dim3(kF / GBN, T / GBM), blk, 0, stream>>>(
        h, w1l, b1 + (size_t)l * kF, nullptr, f, T, kF, kD, 1);
    gemm_kernel<<<dim3(kD / GBN, T / GBM), blk, 0, stream>>>(
        f, w2l, b2 + (size_t)l * kD, x, x, T, kD, kF, 0);
  }

  ln_kernel<<<T, blk, 0, stream>>>(x, fa, fb, out);
}

// Round 3
// 5558.928 us; speedup vs baseline: 3.4580x; 2.0175x over previous
//
#include <hip/hip_runtime.h>
#include <math.h>
#include <stdint.h>

// Problem constants (match reference)
constexpr int kB = 2, kS = 2048, kD = 1024, kH = 16, kF = 4096, kL = 3;
constexpr int kDK = 64;

// bf16 helpers (RNE pack, shift-unpack)
__device__ inline float bf2f(unsigned short u) {
  union { uint32_t i; float f; } v; v.i = (uint32_t)u << 16; return v.f;
}
__device__ inline unsigned short f2bf(float x) {
  union { float f; uint32_t i; } v; v.f = x;
  uint32_t r = v.i + 0x7fffu + ((v.i >> 16) & 1u);
  return (unsigned short)(r >> 16);
}

// ---------------------------------------------------------------------------
// Embedding: x[b,s,:] = emb[tok]*sqrt(D) + pe[s,:]
// ---------------------------------------------------------------------------
__global__ __launch_bounds__(256) void embed_kernel(
    const int* __restrict__ tokens, const float* __restrict__ emb,
    const float* __restrict__ pe, float* __restrict__ x)
{
  int i = blockIdx.x;
  int s = i & (kS - 1);
  int tok = tokens[i];
  const float4* ep = (const float4*)(emb + (size_t)tok * kD);
  const float4* pp = (const float4*)(pe + (size_t)s * kD);
  float4* xp = (float4*)(x + (size_t)i * kD);
  int t = threadIdx.x;
  float4 e = ep[t], p = pp[t];
  xp[t] = make_float4(e.x*32.0f + p.x, e.y*32.0f + p.y,
                      e.z*32.0f + p.z, e.w*32.0f + p.w);
}

// ---------------------------------------------------------------------------
// LayerNorm, torch-style: Bessel-corrected std (ddof=1), eps added to std.
// ---------------------------------------------------------------------------
__global__ __launch_bounds__(256) void ln_kernel(
    const float* __restrict__ x, const float* __restrict__ ga,
    const float* __restrict__ gb, float* __restrict__ out)
{
  int row = blockIdx.x;
  int t = threadIdx.x;
  int lane = t & 63, wid = t >> 6;
  const float4* xp = (const float4*)(x + (size_t)row * kD);
  float4 v = xp[t];
  float s = v.x + v.y + v.z + v.w;
  #pragma unroll
  for (int o = 32; o; o >>= 1) s += __shfl_xor(s, o);
  __shared__ float red[4];
  if (lane == 0) red[wid] = s;
  __syncthreads();
  float mean = (red[0] + red[1] + red[2] + red[3]) * (1.0f / 1024.0f);
  float4 d = make_float4(v.x - mean, v.y - mean, v.z - mean, v.w - mean);
  float ss = d.x*d.x + d.y*d.y + d.z*d.z + d.w*d.w;
  #pragma unroll
  for (int o = 32; o; o >>= 1) ss += __shfl_xor(ss, o);
  __syncthreads();
  if (lane == 0) red[wid] = ss;
  __syncthreads();
  float var = (red[0] + red[1] + red[2] + red[3]) * (1.0f / 1023.0f);
  float inv = 1.0f / (sqrtf(var) + 1e-6f);
  float4 a4 = ((const float4*)ga)[t];
  float4 b4 = ((const float4*)gb)[t];
  float4 o4;
  o4.x = a4.x * d.x * inv + b4.x;
  o4.y = a4.y * d.y * inv + b4.y;
  o4.z = a4.z * d.z * inv + b4.z;
  o4.w = a4.w * d.w * inv + b4.w;
  ((float4*)(out + (size_t)row * kD))[t] = o4;
}

// ---------------------------------------------------------------------------
// SGEMM templated on BN. BM=128, BK=16, 256 threads.
// BN=128: micro 8x8 (grids >=1024 or big-N). BN=64: micro 8x4 — doubles the
// grid for N=1024 matrices so 2 blocks/CU co-schedule (hide barrier drains).
// ---------------------------------------------------------------------------
template<int BN>
__global__ __launch_bounds__(256) void gemm_kernel(
    const float* __restrict__ A, const float* __restrict__ W,
    const float* __restrict__ bias, const float* __restrict__ resid,
    float* __restrict__ out, int M, int N, int K, int relu)
{
  constexpr int NG = BN / 64;            // col groups per thread (1 or 2)
  __shared__ float As[16][128 + 4];
  __shared__ float Bs[16][BN];
  int t = threadIdx.x;
  int tx = t & 15, ty = t >> 4;
  int m0 = blockIdx.y * 128, n0 = blockIdx.x * BN;

  float acc[8][4 * NG];
  #pragma unroll
  for (int i = 0; i < 8; ++i)
    #pragma unroll
    for (int j = 0; j < 4 * NG; ++j) acc[i][j] = 0.0f;

  for (int k0 = 0; k0 < K; k0 += 16) {
    #pragma unroll
    for (int l = 0; l < 2; ++l) {
      int idx = t + 256 * l;
      int row = idx >> 2, c4 = idx & 3;
      float4 a = *(const float4*)&A[(size_t)(m0 + row) * K + k0 + 4 * c4];
      As[4*c4 + 0][row] = a.x;
      As[4*c4 + 1][row] = a.y;
      As[4*c4 + 2][row] = a.z;
      As[4*c4 + 3][row] = a.w;
    }
    #pragma unroll
    for (int l = 0; l < NG; ++l) {
      int idx = t + 256 * l;
      int kr = (BN == 128) ? (idx >> 5) : (idx >> 4);
      int c4 = idx & (BN/4 - 1);
      *(float4*)&Bs[kr][4 * c4] =
          *(const float4*)&W[(size_t)(k0 + kr) * N + n0 + 4 * c4];
    }
    __syncthreads();
    #pragma unroll
    for (int kk = 0; kk < 16; ++kk) {
      float4 a0 = *(const float4*)&As[kk][4 * ty];
      float4 a1 = *(const float4*)&As[kk][64 + 4 * ty];
      float av[8] = {a0.x, a0.y, a0.z, a0.w, a1.x, a1.y, a1.z, a1.w};
      #pragma unroll
      for (int g = 0; g < NG; ++g) {
        float4 b0 = *(const float4*)&Bs[kk][64*g + 4 * tx];
        float bv[4] = {b0.x, b0.y, b0.z, b0.w};
        #pragma unroll
        for (int i = 0; i < 8; ++i)
          #pragma unroll
          for (int j = 0; j < 4; ++j) acc[i][4*g + j] += av[i] * bv[j];
      }
    }
    __syncthreads();
  }

  #pragma unroll
  for (int i = 0; i < 8; ++i) {
    int row = m0 + ((i < 4) ? (4 * ty + i) : (64 + 4 * ty + (i - 4)));
    #pragma unroll
    for (int g = 0; g < NG; ++g) {
      int col = n0 + 64*g + 4 * tx;
      float4 r = make_float4(acc[i][4*g+0], acc[i][4*g+1],
                             acc[i][4*g+2], acc[i][4*g+3]);
      float4 bv = *(const float4*)&bias[col];
      r.x += bv.x; r.y += bv.y; r.z += bv.z; r.w += bv.w;
      if (resid) {
        float4 rv = *(const float4*)&resid[(size_t)row * N + col];
        r.x += rv.x; r.y += rv.y; r.z += rv.z; r.w += rv.w;
      }
      if (relu) {
        r.x = fmaxf(r.x, 0.0f); r.y = fmaxf(r.y, 0.0f);
        r.z = fmaxf(r.z, 0.0f); r.w = fmaxf(r.w, 0.0f);
      }
      *(float4*)&out[(size_t)row * N + col] = r;
    }
  }
}

// ---------------------------------------------------------------------------
// Flash attention v2: block = (b, h, 128-q tile), 256 thr, 64-key chunks.
// tx=t&7 (8 groups), ty=t>>3 (0..31). QK micro 4q x 8k; PV micro 4q x 8d.
// Same row ownership both phases (rows 4ty..4ty+3) -> m/l/alpha live in
// REGISTERS all kernel long. Q staged bf16 [d][q] (pre-scaled), K fp32
// [d][k], V fp32 [k][d], P bf16 [k][q]. LDS = 64KB -> 2 blocks/CU.
// Frag reads are 4-16-way broadcast -> LDS pipe ~1/4 of VALU -> VALU-bound.
// unroll 4 bounds in-flight loads (R1's full unroll caused VGPR spill:
// 6.7GB of scratch HBM traffic).
// ---------------------------------------------------------------------------
__global__ __launch_bounds__(256) void attn_kernel(
    const float* __restrict__ Q, const float* __restrict__ K,
    const float* __restrict__ V, const int* __restrict__ mask,
    float* __restrict__ O)
{
  __shared__ unsigned short Qs[64 * 128];   // [d][q] bf16, pre-scaled 0.125
  __shared__ float          Ks[64 * 64];    // [d][k] fp32
  __shared__ float          Vs[64 * 64];    // [k][d] fp32
  __shared__ unsigned short Ps[64 * 128];   // [k][q] bf16

  int bi = blockIdx.x;
  int qt = bi & 15;
  int h  = (bi >> 4) & 15;
  int b  = bi >> 8;
  int q0 = qt * 128;
  int t = threadIdx.x;
  int tx = t & 7, ty = t >> 3;             // rows 4ty..4ty+3; k/d groups 8tx

  const size_t hbase = (size_t)b * kS * kD + (size_t)h * kDK;

  // ---- stage Q (128 rows x 64 d), transposed to [d][q], bf16, scaled ----
  #pragma unroll
  for (int p = 0; p < 8; ++p) {
    int flat = t + 256 * p;                // 0..2047
    int q = flat & 127, g = flat >> 7;     // g 0..15
    float4 qv = *(const float4*)&Q[hbase + (size_t)(q0 + q) * kD + 4 * g];
    Qs[(4*g + 0) * 128 + q] = f2bf(qv.x * 0.125f);
    Qs[(4*g + 1) * 128 + q] = f2bf(qv.y * 0.125f);
    Qs[(4*g + 2) * 128 + q] = f2bf(qv.z * 0.125f);
    Qs[(4*g + 3) * 128 + q] = f2bf(qv.w * 0.125f);
  }

  float Oacc[4][8];
  float m_i[4], l_i[4];
  #pragma unroll
  for (int i = 0; i < 4; ++i) {
    m_i[i] = -3.0e38f; l_i[i] = 0.0f;
    #pragma unroll
    for (int d = 0; d < 8; ++d) Oacc[i][d] = 0.0f;
  }

  for (int k0 = 0; k0 < kS; k0 += 64) {
    __syncthreads();                       // prev PV readers of Vs/Ps done

    // ---- stage K (transposed [d][k]) and V (direct [k][d]) ----
    #pragma unroll
    for (int p = 0; p < 4; ++p) {
      int flat = t + 256 * p;              // 0..1023
      int kk = flat & 63, g = flat >> 6;   // g 0..15
      float4 kv = *(const float4*)&K[hbase + (size_t)(k0 + kk) * kD + 4 * g];
      Ks[(4*g + 0) * 64 + kk] = kv.x;
      Ks[(4*g + 1) * 64 + kk] = kv.y;
      Ks[(4*g + 2) * 64 + kk] = kv.z;
      Ks[(4*g + 3) * 64 + kk] = kv.w;
      int row = flat >> 4, c = flat & 15;
      float4 vv = *(const float4*)&V[hbase + (size_t)(k0 + row) * kD + 4 * c];
      *(float4*)&Vs[row * 64 + 4 * c] = vv;
    }
    // mask values for this thread's 8 keys (hoisted; L1-served)
    int4 mk0 = *(const int4*)&mask[b * kS + k0 + 8 * tx];
    int4 mk1 = *(const int4*)&mask[b * kS + k0 + 8 * tx + 4];
    __syncthreads();

    // ---- S = Q K^T : 4q x 8k, dot over 64 d ----
    float sacc[4][8];
    #pragma unroll
    for (int i = 0; i < 4; ++i)
      #pragma unroll
      for (int j = 0; j < 8; ++j) sacc[i][j] = 0.0f;

    #pragma unroll 4
    for (int d = 0; d < 64; ++d) {
      ushort4 qu = *(const ushort4*)&Qs[d * 128 + 4 * ty];
      float qf[4] = {bf2f(qu.x), bf2f(qu.y), bf2f(qu.z), bf2f(qu.w)};
      float4 k0v = *(const float4*)&Ks[d * 64 + 8 * tx];
      float4 k1v = *(const float4*)&Ks[d * 64 + 8 * tx + 4];
      float kf[8] = {k0v.x, k0v.y, k0v.z, k0v.w, k1v.x, k1v.y, k1v.z, k1v.w};
      #pragma unroll
      for (int i = 0; i < 4; ++i)
        #pragma unroll
        for (int j = 0; j < 8; ++j) sacc[i][j] += qf[i] * kf[j];
    }

    // mask==0 -> -1e9 (reference semantics, before softmax)
    int mv[8] = {mk0.x, mk0.y, mk0.z, mk0.w, mk1.x, mk1.y, mk1.z, mk1.w};
    #pragma unroll
    for (int j = 0; j < 8; ++j)
      if (mv[j] == 0) {
        #pragma unroll
        for (int i = 0; i < 4; ++i) sacc[i][j] = -1e9f;
      }

    // ---- online softmax; butterfly over the 8 tx lanes (t low 3 bits) ----
    float alpha[4];
    #pragma unroll
    for (int i = 0; i < 4; ++i) {
      float mx = sacc[i][0];
      #pragma unroll
      for (int j = 1; j < 8; ++j) mx = fmaxf(mx, sacc[i][j]);
      #pragma unroll
      for (int o = 1; o < 8; o <<= 1) mx = fmaxf(mx, __shfl_xor(mx, o));
      float newm = fmaxf(m_i[i], mx);
      float rs = 0.0f;
      #pragma unroll
      for (int j = 0; j < 8; ++j) {
        float pv = __expf(sacc[i][j] - newm);
        sacc[i][j] = pv; rs += pv;
      }
      #pragma unroll
      for (int o = 1; o < 8; o <<= 1) rs += __shfl_xor(rs, o);
      alpha[i] = __expf(m_i[i] - newm);
      l_i[i] = l_i[i] * alpha[i] + rs;
      m_i[i] = newm;
    }

    // ---- write P^T to LDS as bf16 [k][q] ----
    #pragma unroll
    for (int j = 0; j < 8; ++j) {
      int kk = 8 * tx + j;
      ushort4 pk = make_ushort4(f2bf(sacc[0][j]), f2bf(sacc[1][j]),
                                f2bf(sacc[2][j]), f2bf(sacc[3][j]));
      *(ushort4*)&Ps[kk * 128 + 4 * ty] = pk;
    }
    __syncthreads();

    // ---- O = O*alpha + P V : 4q x 8d over 64 chunk keys ----
    #pragma unroll
    for (int i = 0; i < 4; ++i)
      #pragma unroll
      for (int d = 0; d < 8; ++d) Oacc[i][d] *= alpha[i];

    #pragma unroll 4
    for (int kk = 0; kk < 64; ++kk) {
      ushort4 pu = *(const ushort4*)&Ps[kk * 128 + 4 * ty];
      float pf[4] = {bf2f(pu.x), bf2f(pu.y), bf2f(pu.z), bf2f(pu.w)};
      float4 v0 = *(const float4*)&Vs[kk * 64 + 8 * tx];
      float4 v1 = *(const float4*)&Vs[kk * 64 + 8 * tx + 4];
      float vf[8] = {v0.x, v0.y, v0.z, v0.w, v1.x, v1.y, v1.z, v1.w};
      #pragma unroll
      for (int i = 0; i < 4; ++i)
        #pragma unroll
        for (int d = 0; d < 8; ++d) Oacc[i][d] += pf[i] * vf[d];
    }
  }

  // ---- epilogue: divide by l, store (256B contiguous per (ty,i)) ----
  #pragma unroll
  for (int i = 0; i < 4; ++i) {
    float inv = 1.0f / l_i[i];
    size_t base = hbase + (size_t)(q0 + 4 * ty + i) * kD + 8 * tx;
    *(float4*)&O[base]     = make_float4(Oacc[i][0]*inv, Oacc[i][1]*inv,
                                         Oacc[i][2]*inv, Oacc[i][3]*inv);
    *(float4*)&O[base + 4] = make_float4(Oacc[i][4]*inv, Oacc[i][5]*inv,
                                         Oacc[i][6]*inv, Oacc[i][7]*inv);
  }
}

// ---------------------------------------------------------------------------
// Orchestration. Workspace (floats), TD = B*S*D = 4M:
//   x:[0,TD)  h:[TD,2TD)  q:[2TD,3TD)  k:[3TD,4TD)  v:[4TD,5TD)
//   f:[2TD, 2TD+B*S*F) aliases q,k,v (dead by FFN). Max 24M floats = 96MB.
// ---------------------------------------------------------------------------
extern "C" void kernel_launch(void* const* d_in, const int* in_sizes, int n_in,
                              void* d_out, int out_size, void* d_ws, size_t ws_size,
                              hipStream_t stream) {
  const int*   tokens = (const int*)d_in[0];
  const int*   mask   = (const int*)d_in[1];
  const float* emb    = (const float*)d_in[2];
  const float* pe     = (const float*)d_in[3];
  const float* Wq     = (const float*)d_in[4];
  const float* bq     = (const float*)d_in[5];
  const float* Wk     = (const float*)d_in[6];
  const float* bk     = (const float*)d_in[7];
  const float* Wv     = (const float*)d_in[8];
  const float* bv     = (const float*)d_in[9];
  const float* Wo     = (const float*)d_in[10];
  const float* bo     = (const float*)d_in[11];
  const float* w1     = (const float*)d_in[12];
  const float* b1     = (const float*)d_in[13];
  const float* w2     = (const float*)d_in[14];
  const float* b2     = (const float*)d_in[15];
  const float* ln_a   = (const float*)d_in[16];
  const float* ln_b   = (const float*)d_in[17];
  const float* fa     = (const float*)d_in[18];
  const float* fb     = (const float*)d_in[19];
  float* out = (float*)d_out;
  float* ws  = (float*)d_ws;

  const int T = kB * kS;               // 4096 rows
  const size_t TD = (size_t)T * kD;
  float* x = ws;
  float* h = ws + TD;
  float* q = ws + 2 * TD;
  float* k = ws + 3 * TD;
  float* v = ws + 4 * TD;
  float* f = ws + 2 * TD;              // aliases q,k,v

  dim3 blk(256);
  embed_kernel<<<T, blk, 0, stream>>>(tokens, emb, pe, x);

  for (int l = 0; l < kL; ++l) {
    const float* Wql = Wq + (size_t)l * kD * kD;
    const float* Wkl = Wk + (size_t)l * kD * kD;
    const float* Wvl = Wv + (size_t)l * kD * kD;
    const float* Wol = Wo + (size_t)l * kD * kD;
    const float* w1l = w1 + (size_t)l * kD * kF;
    const float* w2l = w2 + (size_t)l * kF * kD;

    // --- attention sublayer ---
    ln_kernel<<<T, blk, 0, stream>>>(x, ln_a + (size_t)l * 2 * kD,
                                     ln_b + (size_t)l * 2 * kD, h);
    gemm_kernel<64><<<dim3(kD / 64, T / 128), blk, 0, stream>>>(
        h, Wql, bq + (size_t)l * kD, nullptr, q, T, kD, kD, 0);
    gemm_kernel<64><<<dim3(kD / 64, T / 128), blk, 0, stream>>>(
        h, Wkl, bk + (size_t)l * kD, nullptr, k, T, kD, kD, 0);
    gemm_kernel<64><<<dim3(kD / 64, T / 128), blk, 0, stream>>>(
        h, Wvl, bv + (size_t)l * kD, nullptr, v, T, kD, kD, 0);
    attn_kernel<<<kB * kH * (kS / 128), blk, 0, stream>>>(q, k, v, mask, h);
    gemm_kernel<64><<<dim3(kD / 64, T / 128), blk, 0, stream>>>(
        h, Wol, bo + (size_t)l * kD, x, x, T, kD, kD, 0);

    // --- feed-forward sublayer ---
    ln_kernel<<<T, blk, 0, stream>>>(x, ln_a + (size_t)l * 2 * kD + kD,
                                     ln_b + (size_t)l * 2 * kD + kD, h);
    gemm_kernel<128><<<dim3(kF / 128, T / 128), blk, 0, stream>>>(
        h, w1l, b1 + (size_t)l * kF, nullptr, f, T, kF, kD, 1);
    gemm_kernel<64><<<dim3(kD / 64, T / 128), blk, 0, stream>>>(
        f, w2l, b2 + (size_t)l * kD, x, x, T, kD, kF, 0);
  }

  ln_kernel<<<T, blk, 0, stream>>>(x, fa, fb, out);
}

// Round 4
// 5115.568 us; speedup vs baseline: 3.7577x; 1.0867x over previous
//
#include <hip/hip_runtime.h>
#include <math.h>
#include <stdint.h>

// Problem constants (match reference)
constexpr int kB = 2, kS = 2048, kD = 1024, kH = 16, kF = 4096, kL = 3;
constexpr int kDK = 64;

typedef __attribute__((ext_vector_type(8))) short short8;
typedef __attribute__((ext_vector_type(4))) float floatx4;

// bf16 helpers (RNE pack, shift-unpack)
__device__ inline float bf2f(unsigned short u) {
  union { uint32_t i; float f; } v; v.i = (uint32_t)u << 16; return v.f;
}
__device__ inline unsigned short f2bf(float x) {
  union { float f; uint32_t i; } v; v.f = x;
  uint32_t r = v.i + 0x7fffu + ((v.i >> 16) & 1u);
  return (unsigned short)(r >> 16);
}

// ---------------------------------------------------------------------------
// Embedding: x[b,s,:] = emb[tok]*sqrt(D) + pe[s,:]
// ---------------------------------------------------------------------------
__global__ __launch_bounds__(256) void embed_kernel(
    const int* __restrict__ tokens, const float* __restrict__ emb,
    const float* __restrict__ pe, float* __restrict__ x)
{
  int i = blockIdx.x;
  int s = i & (kS - 1);
  int tok = tokens[i];
  const float4* ep = (const float4*)(emb + (size_t)tok * kD);
  const float4* pp = (const float4*)(pe + (size_t)s * kD);
  float4* xp = (float4*)(x + (size_t)i * kD);
  int t = threadIdx.x;
  float4 e = ep[t], p = pp[t];
  xp[t] = make_float4(e.x*32.0f + p.x, e.y*32.0f + p.y,
                      e.z*32.0f + p.z, e.w*32.0f + p.w);
}

// ---------------------------------------------------------------------------
// LayerNorm (torch-style: Bessel std ddof=1, eps on std) -> fp32 out
// ---------------------------------------------------------------------------
__global__ __launch_bounds__(256) void ln_kernel(
    const float* __restrict__ x, const float* __restrict__ ga,
    const float* __restrict__ gb, float* __restrict__ out)
{
  int row = blockIdx.x;
  int t = threadIdx.x;
  int lane = t & 63, wid = t >> 6;
  const float4* xp = (const float4*)(x + (size_t)row * kD);
  float4 v = xp[t];
  float s = v.x + v.y + v.z + v.w;
  #pragma unroll
  for (int o = 32; o; o >>= 1) s += __shfl_xor(s, o);
  __shared__ float red[4];
  if (lane == 0) red[wid] = s;
  __syncthreads();
  float mean = (red[0] + red[1] + red[2] + red[3]) * (1.0f / 1024.0f);
  float4 d = make_float4(v.x - mean, v.y - mean, v.z - mean, v.w - mean);
  float ss = d.x*d.x + d.y*d.y + d.z*d.z + d.w*d.w;
  #pragma unroll
  for (int o = 32; o; o >>= 1) ss += __shfl_xor(ss, o);
  __syncthreads();
  if (lane == 0) red[wid] = ss;
  __syncthreads();
  float var = (red[0] + red[1] + red[2] + red[3]) * (1.0f / 1023.0f);
  float inv = 1.0f / (sqrtf(var) + 1e-6f);
  float4 a4 = ((const float4*)ga)[t];
  float4 b4 = ((const float4*)gb)[t];
  float4 o4;
  o4.x = a4.x * d.x * inv + b4.x;
  o4.y = a4.y * d.y * inv + b4.y;
  o4.z = a4.z * d.z * inv + b4.z;
  o4.w = a4.w * d.w * inv + b4.w;
  ((float4*)(out + (size_t)row * kD))[t] = o4;
}

// ---------------------------------------------------------------------------
// LayerNorm -> bf16 hi/lo planes (input to split-bf16 MFMA GEMMs)
// ---------------------------------------------------------------------------
__global__ __launch_bounds__(256) void ln_split_kernel(
    const float* __restrict__ x, const float* __restrict__ ga,
    const float* __restrict__ gb, unsigned short* __restrict__ hi,
    unsigned short* __restrict__ lo)
{
  int row = blockIdx.x;
  int t = threadIdx.x;
  int lane = t & 63, wid = t >> 6;
  const float4* xp = (const float4*)(x + (size_t)row * kD);
  float4 v = xp[t];
  float s = v.x + v.y + v.z + v.w;
  #pragma unroll
  for (int o = 32; o; o >>= 1) s += __shfl_xor(s, o);
  __shared__ float red[4];
  if (lane == 0) red[wid] = s;
  __syncthreads();
  float mean = (red[0] + red[1] + red[2] + red[3]) * (1.0f / 1024.0f);
  float4 d = make_float4(v.x - mean, v.y - mean, v.z - mean, v.w - mean);
  float ss = d.x*d.x + d.y*d.y + d.z*d.z + d.w*d.w;
  #pragma unroll
  for (int o = 32; o; o >>= 1) ss += __shfl_xor(ss, o);
  __syncthreads();
  if (lane == 0) red[wid] = ss;
  __syncthreads();
  float var = (red[0] + red[1] + red[2] + red[3]) * (1.0f / 1023.0f);
  float inv = 1.0f / (sqrtf(var) + 1e-6f);
  float4 a4 = ((const float4*)ga)[t];
  float4 b4 = ((const float4*)gb)[t];
  float o0 = a4.x * d.x * inv + b4.x;
  float o1 = a4.y * d.y * inv + b4.y;
  float o2 = a4.z * d.z * inv + b4.z;
  float o3 = a4.w * d.w * inv + b4.w;
  ushort4 h4, l4;
  h4.x = f2bf(o0); l4.x = f2bf(o0 - bf2f(h4.x));
  h4.y = f2bf(o1); l4.y = f2bf(o1 - bf2f(h4.y));
  h4.z = f2bf(o2); l4.z = f2bf(o2 - bf2f(h4.z));
  h4.w = f2bf(o3); l4.w = f2bf(o3 - bf2f(h4.w));
  *(ushort4*)&hi[(size_t)row * kD + 4*t] = h4;
  *(ushort4*)&lo[(size_t)row * kD + 4*t] = l4;
}

// ---------------------------------------------------------------------------
// Weight convert: W[K][N] fp32 -> transposed bf16 hi/lo planes Wt[N][K].
// [N][K] layout makes MFMA B-fragments contiguous 16B LDS reads.
// 64x64 tile via LDS (65-pad: conflict-free transpose read).
// ---------------------------------------------------------------------------
__global__ __launch_bounds__(256) void wconv_kernel(
    const float* __restrict__ W, unsigned short* __restrict__ hi,
    unsigned short* __restrict__ lo, int K, int N)
{
  __shared__ float tile[64][65];
  int n0 = blockIdx.x * 64, k0 = blockIdx.y * 64;
  int c = threadIdx.x & 63, r0 = threadIdx.x >> 6;
  #pragma unroll
  for (int p = 0; p < 16; ++p) {
    int r = r0 + 4 * p;
    tile[r][c] = W[(size_t)(k0 + r) * N + n0 + c];
  }
  __syncthreads();
  #pragma unroll
  for (int p = 0; p < 16; ++p) {
    int nn = r0 + 4 * p;
    float xv = tile[c][nn];                 // = W[k0+c][n0+nn]
    unsigned short h = f2bf(xv);
    size_t o = (size_t)(n0 + nn) * K + k0 + c;
    hi[o] = h;
    lo[o] = f2bf(xv - bf2f(h));
  }
}

// ---------------------------------------------------------------------------
// Split-bf16 MFMA GEMM: out[M,N] = A[M,K] @ W[K,N] (+bias) (+resid) (relu?)
// A given as hi/lo bf16 planes [M][K]; W as hi/lo planes TRANSPOSED [N][K].
// TERMS=3: Ahi*Whi + Ahi*Wlo + Alo*Whi (fp32-grade).  TERMS=2: Ahi*(Whi+Wlo).
// 128x128 tile, BK=32, 4 waves (64x64 each, 4x4 mfma_f32_16x16x32_bf16).
// LDS rows padded to 40 ushorts (80B = 20 words): frag b128 reads cover all
// 32 banks at the 2-phase floor. VGPR prefetch pipelines global loads.
// OUTMODE 0: fp32 (+optional resid). OUTMODE 1: relu -> single bf16 plane.
// ---------------------------------------------------------------------------
template<int TERMS, int OUTMODE>
__global__ __launch_bounds__(256, 2) void mfma_gemm(
    const unsigned short* __restrict__ Ahi, const unsigned short* __restrict__ Alo,
    const unsigned short* __restrict__ Whi, const unsigned short* __restrict__ Wlo,
    const float* __restrict__ bias, const float* __restrict__ resid,
    void* __restrict__ out, int M, int N, int K)
{
  __shared__ unsigned short sAhi[128 * 40];
  __shared__ unsigned short sAlo[128 * 40];
  __shared__ unsigned short sBhi[128 * 40];
  __shared__ unsigned short sBlo[128 * 40];

  int t = threadIdx.x;
  int lane = t & 63, wv = t >> 6;
  int wm = (wv >> 1) * 64, wn = (wv & 1) * 64;
  int lr = lane & 15, lq = lane >> 4;        // tile-row, k-quad (8 bf16)
  int m0 = blockIdx.y * 128, n0 = blockIdx.x * 128;

  // staging: 512 chunks (128 rows x 4 x 16B) per plane; 2 chunks/thread
  int ar0 = t >> 2,          ak0 = (t & 3) * 8;
  int ar1 = (t + 256) >> 2,  ak1 = (t & 3) * 8;   // (t+256)&3 == t&3

  floatx4 acc[4][4];
  #pragma unroll
  for (int i = 0; i < 4; ++i)
    #pragma unroll
    for (int j = 0; j < 4; ++j) acc[i][j] = (floatx4){0.f, 0.f, 0.f, 0.f};

  uint4 pf[8];
  auto issue = [&](int k0) {
    pf[0] = *(const uint4*)&Ahi[(size_t)(m0 + ar0) * K + k0 + ak0];
    pf[1] = *(const uint4*)&Ahi[(size_t)(m0 + ar1) * K + k0 + ak1];
    if (TERMS == 3) {
      pf[2] = *(const uint4*)&Alo[(size_t)(m0 + ar0) * K + k0 + ak0];
      pf[3] = *(const uint4*)&Alo[(size_t)(m0 + ar1) * K + k0 + ak1];
    }
    pf[4] = *(const uint4*)&Whi[(size_t)(n0 + ar0) * K + k0 + ak0];
    pf[5] = *(const uint4*)&Whi[(size_t)(n0 + ar1) * K + k0 + ak1];
    pf[6] = *(const uint4*)&Wlo[(size_t)(n0 + ar0) * K + k0 + ak0];
    pf[7] = *(const uint4*)&Wlo[(size_t)(n0 + ar1) * K + k0 + ak1];
  };
  issue(0);

  for (int k0 = 0; k0 < K; k0 += 32) {
    __syncthreads();
    *(uint4*)&sAhi[ar0 * 40 + ak0] = pf[0];
    *(uint4*)&sAhi[ar1 * 40 + ak1] = pf[1];
    if (TERMS == 3) {
      *(uint4*)&sAlo[ar0 * 40 + ak0] = pf[2];
      *(uint4*)&sAlo[ar1 * 40 + ak1] = pf[3];
    }
    *(uint4*)&sBhi[ar0 * 40 + ak0] = pf[4];
    *(uint4*)&sBhi[ar1 * 40 + ak1] = pf[5];
    *(uint4*)&sBlo[ar0 * 40 + ak0] = pf[6];
    *(uint4*)&sBlo[ar1 * 40 + ak1] = pf[7];
    __syncthreads();
    if (k0 + 32 < K) issue(k0 + 32);   // prefetch next tile during MFMA phase

    short8 a_hi[4], b_hi[4], b_lo[4];
    #pragma unroll
    for (int i = 0; i < 4; ++i)
      a_hi[i] = *(const short8*)&sAhi[(wm + 16*i + lr) * 40 + lq * 8];
    #pragma unroll
    for (int j = 0; j < 4; ++j) {
      b_hi[j] = *(const short8*)&sBhi[(wn + 16*j + lr) * 40 + lq * 8];
      b_lo[j] = *(const short8*)&sBlo[(wn + 16*j + lr) * 40 + lq * 8];
    }
    #pragma unroll
    for (int i = 0; i < 4; ++i)
      #pragma unroll
      for (int j = 0; j < 4; ++j) {
        acc[i][j] = __builtin_amdgcn_mfma_f32_16x16x32_bf16(a_hi[i], b_hi[j], acc[i][j], 0, 0, 0);
        acc[i][j] = __builtin_amdgcn_mfma_f32_16x16x32_bf16(a_hi[i], b_lo[j], acc[i][j], 0, 0, 0);
      }
    if (TERMS == 3) {
      short8 a_lo[4];
      #pragma unroll
      for (int i = 0; i < 4; ++i)
        a_lo[i] = *(const short8*)&sAlo[(wm + 16*i + lr) * 40 + lq * 8];
      #pragma unroll
      for (int i = 0; i < 4; ++i)
        #pragma unroll
        for (int j = 0; j < 4; ++j)
          acc[i][j] = __builtin_amdgcn_mfma_f32_16x16x32_bf16(a_lo[i], b_hi[j], acc[i][j], 0, 0, 0);
    }
  }

  // epilogue: C/D layout col=lane&15, row=(lane>>4)*4+reg  [m89-verified]
  #pragma unroll
  for (int i = 0; i < 4; ++i) {
    #pragma unroll
    for (int j = 0; j < 4; ++j) {
      int col = n0 + wn + 16*j + lr;
      float bv = bias[col];
      #pragma unroll
      for (int r = 0; r < 4; ++r) {
        int row = m0 + wm + 16*i + 4*lq + r;
        float val = acc[i][j][r] + bv;
        if (OUTMODE == 0) {
          if (resid) val += resid[(size_t)row * N + col];
          ((float*)out)[(size_t)row * N + col] = val;
        } else {
          ((unsigned short*)out)[(size_t)row * N + col] = f2bf(fmaxf(val, 0.f));
        }
      }
    }
  }
}

// ---------------------------------------------------------------------------
// Flash attention (unchanged from R3 except epilogue -> bf16 hi/lo planes,
// which feed the Wo split-GEMM directly).
// ---------------------------------------------------------------------------
__global__ __launch_bounds__(256) void attn_kernel(
    const float* __restrict__ Q, const float* __restrict__ K,
    const float* __restrict__ V, const int* __restrict__ mask,
    unsigned short* __restrict__ oHi, unsigned short* __restrict__ oLo)
{
  __shared__ unsigned short Qs[64 * 128];   // [d][q] bf16, pre-scaled 0.125
  __shared__ float          Ks[64 * 64];    // [d][k] fp32
  __shared__ float          Vs[64 * 64];    // [k][d] fp32
  __shared__ unsigned short Ps[64 * 128];   // [k][q] bf16

  int bi = blockIdx.x;
  int qt = bi & 15;
  int h  = (bi >> 4) & 15;
  int b  = bi >> 8;
  int q0 = qt * 128;
  int t = threadIdx.x;
  int tx = t & 7, ty = t >> 3;

  const size_t hbase = (size_t)b * kS * kD + (size_t)h * kDK;

  #pragma unroll
  for (int p = 0; p < 8; ++p) {
    int flat = t + 256 * p;
    int q = flat & 127, g = flat >> 7;
    float4 qv = *(const float4*)&Q[hbase + (size_t)(q0 + q) * kD + 4 * g];
    Qs[(4*g + 0) * 128 + q] = f2bf(qv.x * 0.125f);
    Qs[(4*g + 1) * 128 + q] = f2bf(qv.y * 0.125f);
    Qs[(4*g + 2) * 128 + q] = f2bf(qv.z * 0.125f);
    Qs[(4*g + 3) * 128 + q] = f2bf(qv.w * 0.125f);
  }

  float Oacc[4][8];
  float m_i[4], l_i[4];
  #pragma unroll
  for (int i = 0; i < 4; ++i) {
    m_i[i] = -3.0e38f; l_i[i] = 0.0f;
    #pragma unroll
    for (int d = 0; d < 8; ++d) Oacc[i][d] = 0.0f;
  }

  for (int k0 = 0; k0 < kS; k0 += 64) {
    __syncthreads();

    #pragma unroll
    for (int p = 0; p < 4; ++p) {
      int flat = t + 256 * p;
      int kk = flat & 63, g = flat >> 6;
      float4 kv = *(const float4*)&K[hbase + (size_t)(k0 + kk) * kD + 4 * g];
      Ks[(4*g + 0) * 64 + kk] = kv.x;
      Ks[(4*g + 1) * 64 + kk] = kv.y;
      Ks[(4*g + 2) * 64 + kk] = kv.z;
      Ks[(4*g + 3) * 64 + kk] = kv.w;
      int row = flat >> 4, c = flat & 15;
      float4 vv = *(const float4*)&V[hbase + (size_t)(k0 + row) * kD + 4 * c];
      *(float4*)&Vs[row * 64 + 4 * c] = vv;
    }
    int4 mk0 = *(const int4*)&mask[b * kS + k0 + 8 * tx];
    int4 mk1 = *(const int4*)&mask[b * kS + k0 + 8 * tx + 4];
    __syncthreads();

    float sacc[4][8];
    #pragma unroll
    for (int i = 0; i < 4; ++i)
      #pragma unroll
      for (int j = 0; j < 8; ++j) sacc[i][j] = 0.0f;

    #pragma unroll 4
    for (int d = 0; d < 64; ++d) {
      ushort4 qu = *(const ushort4*)&Qs[d * 128 + 4 * ty];
      float qf[4] = {bf2f(qu.x), bf2f(qu.y), bf2f(qu.z), bf2f(qu.w)};
      float4 k0v = *(const float4*)&Ks[d * 64 + 8 * tx];
      float4 k1v = *(const float4*)&Ks[d * 64 + 8 * tx + 4];
      float kf[8] = {k0v.x, k0v.y, k0v.z, k0v.w, k1v.x, k1v.y, k1v.z, k1v.w};
      #pragma unroll
      for (int i = 0; i < 4; ++i)
        #pragma unroll
        for (int j = 0; j < 8; ++j) sacc[i][j] += qf[i] * kf[j];
    }

    int mv[8] = {mk0.x, mk0.y, mk0.z, mk0.w, mk1.x, mk1.y, mk1.z, mk1.w};
    #pragma unroll
    for (int j = 0; j < 8; ++j)
      if (mv[j] == 0) {
        #pragma unroll
        for (int i = 0; i < 4; ++i) sacc[i][j] = -1e9f;
      }

    float alpha[4];
    #pragma unroll
    for (int i = 0; i < 4; ++i) {
      float mx = sacc[i][0];
      #pragma unroll
      for (int j = 1; j < 8; ++j) mx = fmaxf(mx, sacc[i][j]);
      #pragma unroll
      for (int o = 1; o < 8; o <<= 1) mx = fmaxf(mx, __shfl_xor(mx, o));
      float newm = fmaxf(m_i[i], mx);
      float rs = 0.0f;
      #pragma unroll
      for (int j = 0; j < 8; ++j) {
        float pv = __expf(sacc[i][j] - newm);
        sacc[i][j] = pv; rs += pv;
      }
      #pragma unroll
      for (int o = 1; o < 8; o <<= 1) rs += __shfl_xor(rs, o);
      alpha[i] = __expf(m_i[i] - newm);
      l_i[i] = l_i[i] * alpha[i] + rs;
      m_i[i] = newm;
    }

    #pragma unroll
    for (int j = 0; j < 8; ++j) {
      int kk = 8 * tx + j;
      ushort4 pk = make_ushort4(f2bf(sacc[0][j]), f2bf(sacc[1][j]),
                                f2bf(sacc[2][j]), f2bf(sacc[3][j]));
      *(ushort4*)&Ps[kk * 128 + 4 * ty] = pk;
    }
    __syncthreads();

    #pragma unroll
    for (int i = 0; i < 4; ++i)
      #pragma unroll
      for (int d = 0; d < 8; ++d) Oacc[i][d] *= alpha[i];

    #pragma unroll 4
    for (int kk = 0; kk < 64; ++kk) {
      ushort4 pu = *(const ushort4*)&Ps[kk * 128 + 4 * ty];
      float pf[4] = {bf2f(pu.x), bf2f(pu.y), bf2f(pu.z), bf2f(pu.w)};
      float4 v0 = *(const float4*)&Vs[kk * 64 + 8 * tx];
      float4 v1 = *(const float4*)&Vs[kk * 64 + 8 * tx + 4];
      float vf[8] = {v0.x, v0.y, v0.z, v0.w, v1.x, v1.y, v1.z, v1.w};
      #pragma unroll
      for (int i = 0; i < 4; ++i)
        #pragma unroll
        for (int d = 0; d < 8; ++d) Oacc[i][d] += pf[i] * vf[d];
    }
  }

  // epilogue: o -> bf16 hi/lo planes (input of Wo split-GEMM)
  #pragma unroll
  for (int i = 0; i < 4; ++i) {
    float inv = 1.0f / l_i[i];
    size_t base = hbase + (size_t)(q0 + 4 * ty + i) * kD + 8 * tx;
    float vals[8];
    #pragma unroll
    for (int d = 0; d < 8; ++d) vals[d] = Oacc[i][d] * inv;
    ushort4 h0, h1, l0, l1;
    h0.x = f2bf(vals[0]); l0.x = f2bf(vals[0] - bf2f(h0.x));
    h0.y = f2bf(vals[1]); l0.y = f2bf(vals[1] - bf2f(h0.y));
    h0.z = f2bf(vals[2]); l0.z = f2bf(vals[2] - bf2f(h0.z));
    h0.w = f2bf(vals[3]); l0.w = f2bf(vals[3] - bf2f(h0.w));
    h1.x = f2bf(vals[4]); l1.x = f2bf(vals[4] - bf2f(h1.x));
    h1.y = f2bf(vals[5]); l1.y = f2bf(vals[5] - bf2f(h1.y));
    h1.z = f2bf(vals[6]); l1.z = f2bf(vals[6] - bf2f(h1.z));
    h1.w = f2bf(vals[7]); l1.w = f2bf(vals[7] - bf2f(h1.w));
    *(ushort4*)&oHi[base]     = h0;
    *(ushort4*)&oHi[base + 4] = h1;
    *(ushort4*)&oLo[base]     = l0;
    *(ushort4*)&oLo[base + 4] = l1;
  }
}

// ---------------------------------------------------------------------------
// Orchestration. Workspace byte layout (total 96 MiB — same as R0's proven):
//   x      [ 0MB,16MB) fp32 4M
//   hHi    [16MB,24MB) ushort 4M     hLo [24MB,32MB)
//   big    [32MB,80MB): q/k/v fp32 (16MB each) during attention;
//                       f bf16 plane [32MB,64MB) during FFN
//   Wbuf   [80MB,96MB): rotating weight hi/lo planes (QKVO: 4MB slots;
//                       w1/w2: full 16MB, hi then lo)
// ---------------------------------------------------------------------------
extern "C" void kernel_launch(void* const* d_in, const int* in_sizes, int n_in,
                              void* d_out, int out_size, void* d_ws, size_t ws_size,
                              hipStream_t stream) {
  const int*   tokens = (const int*)d_in[0];
  const int*   mask   = (const int*)d_in[1];
  const float* emb    = (const float*)d_in[2];
  const float* pe     = (const float*)d_in[3];
  const float* Wq     = (const float*)d_in[4];
  const float* bq     = (const float*)d_in[5];
  const float* Wk     = (const float*)d_in[6];
  const float* bk     = (const float*)d_in[7];
  const float* Wv     = (const float*)d_in[8];
  const float* bv     = (const float*)d_in[9];
  const float* Wo     = (const float*)d_in[10];
  const float* bo     = (const float*)d_in[11];
  const float* w1     = (const float*)d_in[12];
  const float* b1     = (const float*)d_in[13];
  const float* w2     = (const float*)d_in[14];
  const float* b2     = (const float*)d_in[15];
  const float* ln_a   = (const float*)d_in[16];
  const float* ln_b   = (const float*)d_in[17];
  const float* fa     = (const float*)d_in[18];
  const float* fb     = (const float*)d_in[19];
  float* out = (float*)d_out;
  char*  ws  = (char*)d_ws;

  const int T = kB * kS;                       // 4096 rows
  constexpr size_t MB = 1024 * 1024;

  float*          x    = (float*)(ws);
  unsigned short* hHi  = (unsigned short*)(ws + 16 * MB);
  unsigned short* hLo  = (unsigned short*)(ws + 24 * MB);
  float*          q    = (float*)(ws + 32 * MB);
  float*          k    = (float*)(ws + 48 * MB);
  float*          v    = (float*)(ws + 64 * MB);
  unsigned short* fpln = (unsigned short*)(ws + 32 * MB);   // aliases q,k
  char*           Wbuf = ws + 80 * MB;

  dim3 blk(256);
  embed_kernel<<<T, blk, 0, stream>>>(tokens, emb, pe, x);

  for (int l = 0; l < kL; ++l) {
    const float* Wql = Wq + (size_t)l * kD * kD;
    const float* Wkl = Wk + (size_t)l * kD * kD;
    const float* Wvl = Wv + (size_t)l * kD * kD;
    const float* Wol = Wo + (size_t)l * kD * kD;
    const float* w1l = w1 + (size_t)l * kD * kF;
    const float* w2l = w2 + (size_t)l * kF * kD;

    // --- convert QKVO weights into 4 x 4MB slots (hi,lo per slot) ---
    unsigned short* sq_hi = (unsigned short*)(Wbuf + 0 * MB);
    unsigned short* sq_lo = (unsigned short*)(Wbuf + 2 * MB);
    unsigned short* sk_hi = (unsigned short*)(Wbuf + 4 * MB);
    unsigned short* sk_lo = (unsigned short*)(Wbuf + 6 * MB);
    unsigned short* sv_hi = (unsigned short*)(Wbuf + 8 * MB);
    unsigned short* sv_lo = (unsigned short*)(Wbuf + 10 * MB);
    unsigned short* so_hi = (unsigned short*)(Wbuf + 12 * MB);
    unsigned short* so_lo = (unsigned short*)(Wbuf + 14 * MB);
    wconv_kernel<<<dim3(kD/64, kD/64), blk, 0, stream>>>(Wql, sq_hi, sq_lo, kD, kD);
    wconv_kernel<<<dim3(kD/64, kD/64), blk, 0, stream>>>(Wkl, sk_hi, sk_lo, kD, kD);
    wconv_kernel<<<dim3(kD/64, kD/64), blk, 0, stream>>>(Wvl, sv_hi, sv_lo, kD, kD);
    wconv_kernel<<<dim3(kD/64, kD/64), blk, 0, stream>>>(Wol, so_hi, so_lo, kD, kD);

    // --- attention sublayer ---
    ln_split_kernel<<<T, blk, 0, stream>>>(x, ln_a + (size_t)l * 2 * kD,
                                           ln_b + (size_t)l * 2 * kD, hHi, hLo);
    mfma_gemm<3,0><<<dim3(kD/128, T/128), blk, 0, stream>>>(
        hHi, hLo, sq_hi, sq_lo, bq + (size_t)l * kD, nullptr, q, T, kD, kD);
    mfma_gemm<3,0><<<dim3(kD/128, T/128), blk, 0, stream>>>(
        hHi, hLo, sk_hi, sk_lo, bk + (size_t)l * kD, nullptr, k, T, kD, kD);
    mfma_gemm<3,0><<<dim3(kD/128, T/128), blk, 0, stream>>>(
        hHi, hLo, sv_hi, sv_lo, bv + (size_t)l * kD, nullptr, v, T, kD, kD);
    attn_kernel<<<kB * kH * (kS / 128), blk, 0, stream>>>(q, k, v, mask, hHi, hLo);
    mfma_gemm<3,0><<<dim3(kD/128, T/128), blk, 0, stream>>>(
        hHi, hLo, so_hi, so_lo, bo + (size_t)l * kD, x, x, T, kD, kD);

    // --- feed-forward sublayer ---
    ln_split_kernel<<<T, blk, 0, stream>>>(x, ln_a + (size_t)l * 2 * kD + kD,
                                           ln_b + (size_t)l * 2 * kD + kD, hHi, hLo);
    unsigned short* w1_hi = (unsigned short*)(Wbuf);
    unsigned short* w1_lo = (unsigned short*)(Wbuf + 8 * MB);
    wconv_kernel<<<dim3(kF/64, kD/64), blk, 0, stream>>>(w1l, w1_hi, w1_lo, kD, kF);
    mfma_gemm<3,1><<<dim3(kF/128, T/128), blk, 0, stream>>>(
        hHi, hLo, w1_hi, w1_lo, b1 + (size_t)l * kF, nullptr, fpln, T, kF, kD);
    unsigned short* w2_hi = (unsigned short*)(Wbuf);
    unsigned short* w2_lo = (unsigned short*)(Wbuf + 8 * MB);
    wconv_kernel<<<dim3(kD/64, kF/64), blk, 0, stream>>>(w2l, w2_hi, w2_lo, kF, kD);
    mfma_gemm<2,0><<<dim3(kD/128, T/128), blk, 0, stream>>>(
        fpln, nullptr, w2_hi, w2_lo, b2 + (size_t)l * kD, x, x, T, kD, kF);
  }

  ln_kernel<<<T, blk, 0, stream>>>(x, fa, fb, out);
}

// Round 5
// 4148.458 us; speedup vs baseline: 4.6337x; 1.2331x over previous
//
#include <hip/hip_runtime.h>
#include <math.h>
#include <stdint.h>

// Problem constants (match reference)
constexpr int kB = 2, kS = 2048, kD = 1024, kH = 16, kF = 4096, kL = 3;
constexpr int kDK = 64;

typedef __attribute__((ext_vector_type(8))) short short8;
typedef __attribute__((ext_vector_type(4))) float floatx4;

// bf16 helpers (RNE pack, shift-unpack)
__device__ inline float bf2f(unsigned short u) {
  union { uint32_t i; float f; } v; v.i = (uint32_t)u << 16; return v.f;
}
__device__ inline unsigned short f2bf(float x) {
  union { float f; uint32_t i; } v; v.f = x;
  uint32_t r = v.i + 0x7fffu + ((v.i >> 16) & 1u);
  return (unsigned short)(r >> 16);
}

// ---------------------------------------------------------------------------
// Embedding: x[b,s,:] = emb[tok]*sqrt(D) + pe[s,:]
// ---------------------------------------------------------------------------
__global__ __launch_bounds__(256) void embed_kernel(
    const int* __restrict__ tokens, const float* __restrict__ emb,
    const float* __restrict__ pe, float* __restrict__ x)
{
  int i = blockIdx.x;
  int s = i & (kS - 1);
  int tok = tokens[i];
  const float4* ep = (const float4*)(emb + (size_t)tok * kD);
  const float4* pp = (const float4*)(pe + (size_t)s * kD);
  float4* xp = (float4*)(x + (size_t)i * kD);
  int t = threadIdx.x;
  float4 e = ep[t], p = pp[t];
  xp[t] = make_float4(e.x*32.0f + p.x, e.y*32.0f + p.y,
                      e.z*32.0f + p.z, e.w*32.0f + p.w);
}

// ---------------------------------------------------------------------------
// LayerNorm (torch-style: Bessel std ddof=1, eps on std) -> fp32 out
// ---------------------------------------------------------------------------
__global__ __launch_bounds__(256) void ln_kernel(
    const float* __restrict__ x, const float* __restrict__ ga,
    const float* __restrict__ gb, float* __restrict__ out)
{
  int row = blockIdx.x;
  int t = threadIdx.x;
  int lane = t & 63, wid = t >> 6;
  const float4* xp = (const float4*)(x + (size_t)row * kD);
  float4 v = xp[t];
  float s = v.x + v.y + v.z + v.w;
  #pragma unroll
  for (int o = 32; o; o >>= 1) s += __shfl_xor(s, o);
  __shared__ float red[4];
  if (lane == 0) red[wid] = s;
  __syncthreads();
  float mean = (red[0] + red[1] + red[2] + red[3]) * (1.0f / 1024.0f);
  float4 d = make_float4(v.x - mean, v.y - mean, v.z - mean, v.w - mean);
  float ss = d.x*d.x + d.y*d.y + d.z*d.z + d.w*d.w;
  #pragma unroll
  for (int o = 32; o; o >>= 1) ss += __shfl_xor(ss, o);
  __syncthreads();
  if (lane == 0) red[wid] = ss;
  __syncthreads();
  float var = (red[0] + red[1] + red[2] + red[3]) * (1.0f / 1023.0f);
  float inv = 1.0f / (sqrtf(var) + 1e-6f);
  float4 a4 = ((const float4*)ga)[t];
  float4 b4 = ((const float4*)gb)[t];
  float4 o4;
  o4.x = a4.x * d.x * inv + b4.x;
  o4.y = a4.y * d.y * inv + b4.y;
  o4.z = a4.z * d.z * inv + b4.z;
  o4.w = a4.w * d.w * inv + b4.w;
  ((float4*)(out + (size_t)row * kD))[t] = o4;
}

// ---------------------------------------------------------------------------
// LayerNorm -> bf16 hi/lo planes (input to split-bf16 MFMA GEMMs)
// ---------------------------------------------------------------------------
__global__ __launch_bounds__(256) void ln_split_kernel(
    const float* __restrict__ x, const float* __restrict__ ga,
    const float* __restrict__ gb, unsigned short* __restrict__ hi,
    unsigned short* __restrict__ lo)
{
  int row = blockIdx.x;
  int t = threadIdx.x;
  int lane = t & 63, wid = t >> 6;
  const float4* xp = (const float4*)(x + (size_t)row * kD);
  float4 v = xp[t];
  float s = v.x + v.y + v.z + v.w;
  #pragma unroll
  for (int o = 32; o; o >>= 1) s += __shfl_xor(s, o);
  __shared__ float red[4];
  if (lane == 0) red[wid] = s;
  __syncthreads();
  float mean = (red[0] + red[1] + red[2] + red[3]) * (1.0f / 1024.0f);
  float4 d = make_float4(v.x - mean, v.y - mean, v.z - mean, v.w - mean);
  float ss = d.x*d.x + d.y*d.y + d.z*d.z + d.w*d.w;
  #pragma unroll
  for (int o = 32; o; o >>= 1) ss += __shfl_xor(ss, o);
  __syncthreads();
  if (lane == 0) red[wid] = ss;
  __syncthreads();
  float var = (red[0] + red[1] + red[2] + red[3]) * (1.0f / 1023.0f);
  float inv = 1.0f / (sqrtf(var) + 1e-6f);
  float4 a4 = ((const float4*)ga)[t];
  float4 b4 = ((const float4*)gb)[t];
  float o0 = a4.x * d.x * inv + b4.x;
  float o1 = a4.y * d.y * inv + b4.y;
  float o2 = a4.z * d.z * inv + b4.z;
  float o3 = a4.w * d.w * inv + b4.w;
  ushort4 h4, l4;
  h4.x = f2bf(o0); l4.x = f2bf(o0 - bf2f(h4.x));
  h4.y = f2bf(o1); l4.y = f2bf(o1 - bf2f(h4.y));
  h4.z = f2bf(o2); l4.z = f2bf(o2 - bf2f(h4.z));
  h4.w = f2bf(o3); l4.w = f2bf(o3 - bf2f(h4.w));
  *(ushort4*)&hi[(size_t)row * kD + 4*t] = h4;
  *(ushort4*)&lo[(size_t)row * kD + 4*t] = l4;
}

// ---------------------------------------------------------------------------
// Weight convert: W[K][N] fp32 -> transposed bf16 hi/lo planes Wt[N][K].
// ---------------------------------------------------------------------------
__global__ __launch_bounds__(256) void wconv_kernel(
    const float* __restrict__ W, unsigned short* __restrict__ hi,
    unsigned short* __restrict__ lo, int K, int N)
{
  __shared__ float tile[64][65];
  int n0 = blockIdx.x * 64, k0 = blockIdx.y * 64;
  int c = threadIdx.x & 63, r0 = threadIdx.x >> 6;
  #pragma unroll
  for (int p = 0; p < 16; ++p) {
    int r = r0 + 4 * p;
    tile[r][c] = W[(size_t)(k0 + r) * N + n0 + c];
  }
  __syncthreads();
  #pragma unroll
  for (int p = 0; p < 16; ++p) {
    int nn = r0 + 4 * p;
    float xv = tile[c][nn];                 // = W[k0+c][n0+nn]
    unsigned short h = f2bf(xv);
    size_t o = (size_t)(n0 + nn) * K + k0 + c;
    hi[o] = h;
    lo[o] = f2bf(xv - bf2f(h));
  }
}

// ---------------------------------------------------------------------------
// Split-bf16 MFMA GEMM (see R4 notes). OUTMODE 0: fp32 (+resid).
// OUTMODE 1: relu -> bf16 plane.  OUTMODE 2: bf16 plane, no relu (QKV out).
// ---------------------------------------------------------------------------
template<int TERMS, int OUTMODE>
__global__ __launch_bounds__(256, 2) void mfma_gemm(
    const unsigned short* __restrict__ Ahi, const unsigned short* __restrict__ Alo,
    const unsigned short* __restrict__ Whi, const unsigned short* __restrict__ Wlo,
    const float* __restrict__ bias, const float* __restrict__ resid,
    void* __restrict__ out, int M, int N, int K)
{
  __shared__ unsigned short sAhi[128 * 40];
  __shared__ unsigned short sAlo[128 * 40];
  __shared__ unsigned short sBhi[128 * 40];
  __shared__ unsigned short sBlo[128 * 40];

  int t = threadIdx.x;
  int lane = t & 63, wv = t >> 6;
  int wm = (wv >> 1) * 64, wn = (wv & 1) * 64;
  int lr = lane & 15, lq = lane >> 4;
  int m0 = blockIdx.y * 128, n0 = blockIdx.x * 128;

  int ar0 = t >> 2,          ak0 = (t & 3) * 8;
  int ar1 = (t + 256) >> 2,  ak1 = (t & 3) * 8;

  floatx4 acc[4][4];
  #pragma unroll
  for (int i = 0; i < 4; ++i)
    #pragma unroll
    for (int j = 0; j < 4; ++j) acc[i][j] = (floatx4){0.f, 0.f, 0.f, 0.f};

  uint4 pf[8];
  auto issue = [&](int k0) {
    pf[0] = *(const uint4*)&Ahi[(size_t)(m0 + ar0) * K + k0 + ak0];
    pf[1] = *(const uint4*)&Ahi[(size_t)(m0 + ar1) * K + k0 + ak1];
    if (TERMS == 3) {
      pf[2] = *(const uint4*)&Alo[(size_t)(m0 + ar0) * K + k0 + ak0];
      pf[3] = *(const uint4*)&Alo[(size_t)(m0 + ar1) * K + k0 + ak1];
    }
    pf[4] = *(const uint4*)&Whi[(size_t)(n0 + ar0) * K + k0 + ak0];
    pf[5] = *(const uint4*)&Whi[(size_t)(n0 + ar1) * K + k0 + ak1];
    pf[6] = *(const uint4*)&Wlo[(size_t)(n0 + ar0) * K + k0 + ak0];
    pf[7] = *(const uint4*)&Wlo[(size_t)(n0 + ar1) * K + k0 + ak1];
  };
  issue(0);

  for (int k0 = 0; k0 < K; k0 += 32) {
    __syncthreads();
    *(uint4*)&sAhi[ar0 * 40 + ak0] = pf[0];
    *(uint4*)&sAhi[ar1 * 40 + ak1] = pf[1];
    if (TERMS == 3) {
      *(uint4*)&sAlo[ar0 * 40 + ak0] = pf[2];
      *(uint4*)&sAlo[ar1 * 40 + ak1] = pf[3];
    }
    *(uint4*)&sBhi[ar0 * 40 + ak0] = pf[4];
    *(uint4*)&sBhi[ar1 * 40 + ak1] = pf[5];
    *(uint4*)&sBlo[ar0 * 40 + ak0] = pf[6];
    *(uint4*)&sBlo[ar1 * 40 + ak1] = pf[7];
    __syncthreads();
    if (k0 + 32 < K) issue(k0 + 32);

    short8 a_hi[4], b_hi[4], b_lo[4];
    #pragma unroll
    for (int i = 0; i < 4; ++i)
      a_hi[i] = *(const short8*)&sAhi[(wm + 16*i + lr) * 40 + lq * 8];
    #pragma unroll
    for (int j = 0; j < 4; ++j) {
      b_hi[j] = *(const short8*)&sBhi[(wn + 16*j + lr) * 40 + lq * 8];
      b_lo[j] = *(const short8*)&sBlo[(wn + 16*j + lr) * 40 + lq * 8];
    }
    #pragma unroll
    for (int i = 0; i < 4; ++i)
      #pragma unroll
      for (int j = 0; j < 4; ++j) {
        acc[i][j] = __builtin_amdgcn_mfma_f32_16x16x32_bf16(a_hi[i], b_hi[j], acc[i][j], 0, 0, 0);
        acc[i][j] = __builtin_amdgcn_mfma_f32_16x16x32_bf16(a_hi[i], b_lo[j], acc[i][j], 0, 0, 0);
      }
    if (TERMS == 3) {
      short8 a_lo[4];
      #pragma unroll
      for (int i = 0; i < 4; ++i)
        a_lo[i] = *(const short8*)&sAlo[(wm + 16*i + lr) * 40 + lq * 8];
      #pragma unroll
      for (int i = 0; i < 4; ++i)
        #pragma unroll
        for (int j = 0; j < 4; ++j)
          acc[i][j] = __builtin_amdgcn_mfma_f32_16x16x32_bf16(a_lo[i], b_hi[j], acc[i][j], 0, 0, 0);
    }
  }

  // epilogue: C/D layout col=lane&15, row=(lane>>4)*4+reg
  #pragma unroll
  for (int i = 0; i < 4; ++i) {
    #pragma unroll
    for (int j = 0; j < 4; ++j) {
      int col = n0 + wn + 16*j + lr;
      float bv = bias[col];
      #pragma unroll
      for (int r = 0; r < 4; ++r) {
        int row = m0 + wm + 16*i + 4*lq + r;
        float val = acc[i][j][r] + bv;
        if (OUTMODE == 0) {
          if (resid) val += resid[(size_t)row * N + col];
          ((float*)out)[(size_t)row * N + col] = val;
        } else if (OUTMODE == 1) {
          ((unsigned short*)out)[(size_t)row * N + col] = f2bf(fmaxf(val, 0.f));
        } else {
          ((unsigned short*)out)[(size_t)row * N + col] = f2bf(val);
        }
      }
    }
  }
}

// ---------------------------------------------------------------------------
// MFMA flash attention. Block = (b,h,128q), 4 waves x 32q rows, 64-key chunks.
// Q/K/V arrive as bf16 (written by the QKV GEMMs). All LDS tiles stride 72
// ushorts (144B): b128-aligned, 2-way bank alias (free, m136). S-scale 0.125
// applied to accumulators (exact pow2), then mask -> -1e9 (ref semantics).
// C-layout row = 4*quad+r is IDENTICAL for S and O accs -> m/l/alpha stay in
// registers; P round-trips LDS wave-privately (rows 32w..32w+31) -> no extra
// barrier. LDS 54KB -> 2 blocks/CU (= the 512-block grid's residency).
// ---------------------------------------------------------------------------
#define ASTR 72

__global__ __launch_bounds__(256) void attn_kernel(
    const unsigned short* __restrict__ Qg, const unsigned short* __restrict__ Kg,
    const unsigned short* __restrict__ Vg, const int* __restrict__ mask,
    unsigned short* __restrict__ oHi, unsigned short* __restrict__ oLo)
{
  __shared__ unsigned short Qs[128 * ASTR];  // [q][d]
  __shared__ unsigned short Ks[64 * ASTR];   // [k][d]
  __shared__ unsigned short Vs[64 * ASTR];   // [d][k] (transposed)
  __shared__ unsigned short Ps[128 * ASTR];  // [q][k]

  int bi = blockIdx.x;
  int qt = bi & 15;
  int h  = (bi >> 4) & 15;
  int b  = bi >> 8;
  int q0 = qt * 128;
  int t = threadIdx.x;
  int lane = t & 63, wv = t >> 6;
  int lr = lane & 15, lq = lane >> 4;
  int wq = wv * 32;                          // wave's q-row base in tile

  const size_t hbase = (size_t)b * kS * kD + (size_t)h * kDK;

  // ---- stage Q: 128 rows x 8 ushort8-chunks = 1024 chunks, 4/thread ----
  #pragma unroll
  for (int p = 0; p < 4; ++p) {
    int c = t + 256 * p;
    int row = c >> 3, dq = c & 7;
    *(uint4*)&Qs[row * ASTR + 8 * dq] =
        *(const uint4*)&Qg[hbase + (size_t)(q0 + row) * kD + 8 * dq];
  }

  floatx4 Oacc[2][4];
  float m_i[2][4], l_i[2][4];
  #pragma unroll
  for (int i = 0; i < 2; ++i)
    #pragma unroll
    for (int r = 0; r < 4; ++r) {
      m_i[i][r] = -3.0e38f; l_i[i][r] = 0.0f;
    }
  #pragma unroll
  for (int i = 0; i < 2; ++i)
    #pragma unroll
    for (int j = 0; j < 4; ++j) Oacc[i][j] = (floatx4){0.f, 0.f, 0.f, 0.f};

  for (int k0 = 0; k0 < kS; k0 += 64) {
    __syncthreads();                         // prev chunk's Ks/Vs readers done

    // ---- stage K [k][d] and V transposed [d][k]: 512 chunks, 2/thread ----
    #pragma unroll
    for (int p = 0; p < 2; ++p) {
      int c = t + 256 * p;
      int row = c >> 3, dq = c & 7;
      size_t g = hbase + (size_t)(k0 + row) * kD + 8 * dq;
      *(uint4*)&Ks[row * ASTR + 8 * dq] = *(const uint4*)&Kg[g];
      uint4 vv = *(const uint4*)&Vg[g];
      const unsigned short* vs = (const unsigned short*)&vv;
      #pragma unroll
      for (int j = 0; j < 8; ++j)
        Vs[(8 * dq + j) * ASTR + row] = vs[j];
    }
    // mask for this lane's 4 owned key-columns (16j + lr)
    int mv[4];
    #pragma unroll
    for (int j = 0; j < 4; ++j) mv[j] = mask[b * kS + k0 + 16*j + lr];
    __syncthreads();

    // ---- S = Q K^T (MFMA): 2 q-tiles x 4 k-tiles x 2 k-steps ----
    floatx4 sac[2][4];
    #pragma unroll
    for (int i = 0; i < 2; ++i)
      #pragma unroll
      for (int j = 0; j < 4; ++j) sac[i][j] = (floatx4){0.f, 0.f, 0.f, 0.f};
    #pragma unroll
    for (int ks = 0; ks < 2; ++ks) {
      short8 af[2], bf[4];
      #pragma unroll
      for (int i = 0; i < 2; ++i)
        af[i] = *(const short8*)&Qs[(wq + 16*i + lr) * ASTR + 32*ks + 8*lq];
      #pragma unroll
      for (int j = 0; j < 4; ++j)
        bf[j] = *(const short8*)&Ks[(16*j + lr) * ASTR + 32*ks + 8*lq];
      #pragma unroll
      for (int i = 0; i < 2; ++i)
        #pragma unroll
        for (int j = 0; j < 4; ++j)
          sac[i][j] = __builtin_amdgcn_mfma_f32_16x16x32_bf16(af[i], bf[j], sac[i][j], 0, 0, 0);
    }

    // scale (exact pow2) then mask
    #pragma unroll
    for (int i = 0; i < 2; ++i)
      #pragma unroll
      for (int j = 0; j < 4; ++j) {
        #pragma unroll
        for (int r = 0; r < 4; ++r) sac[i][j][r] *= 0.125f;
        if (mv[j] == 0)
          #pragma unroll
          for (int r = 0; r < 4; ++r) sac[i][j][r] = -1e9f;
      }

    // ---- online softmax: row = wq+16i+4lq+r, owners = 16 lanes of quad lq ----
    float alf[2][4];
    #pragma unroll
    for (int i = 0; i < 2; ++i)
      #pragma unroll
      for (int r = 0; r < 4; ++r) {
        float mx = fmaxf(fmaxf(sac[i][0][r], sac[i][1][r]),
                         fmaxf(sac[i][2][r], sac[i][3][r]));
        #pragma unroll
        for (int o = 1; o < 16; o <<= 1) mx = fmaxf(mx, __shfl_xor(mx, o));
        float newm = fmaxf(m_i[i][r], mx);
        float rs = 0.0f;
        #pragma unroll
        for (int j = 0; j < 4; ++j) {
          float e = __expf(sac[i][j][r] - newm);
          sac[i][j][r] = e; rs += e;
        }
        #pragma unroll
        for (int o = 1; o < 16; o <<= 1) rs += __shfl_xor(rs, o);
        alf[i][r] = __expf(m_i[i][r] - newm);
        l_i[i][r] = l_i[i][r] * alf[i][r] + rs;
        m_i[i][r] = newm;
      }

    // ---- P -> LDS bf16 [q][k] (wave-private rows; no barrier needed) ----
    #pragma unroll
    for (int i = 0; i < 2; ++i)
      #pragma unroll
      for (int j = 0; j < 4; ++j)
        #pragma unroll
        for (int r = 0; r < 4; ++r)
          Ps[(wq + 16*i + 4*lq + r) * ASTR + 16*j + lr] = f2bf(sac[i][j][r]);

    // rescale O by alpha (same row ownership as S)
    #pragma unroll
    for (int i = 0; i < 2; ++i)
      #pragma unroll
      for (int j = 0; j < 4; ++j)
        #pragma unroll
        for (int r = 0; r < 4; ++r) Oacc[i][j][r] *= alf[i][r];

    // ---- O += P V (MFMA): 2 q-tiles x 4 d-tiles x 2 k-steps ----
    #pragma unroll
    for (int ks = 0; ks < 2; ++ks) {
      short8 pa[2], vb[4];
      #pragma unroll
      for (int i = 0; i < 2; ++i)
        pa[i] = *(const short8*)&Ps[(wq + 16*i + lr) * ASTR + 32*ks + 8*lq];
      #pragma unroll
      for (int j = 0; j < 4; ++j)
        vb[j] = *(const short8*)&Vs[(16*j + lr) * ASTR + 32*ks + 8*lq];
      #pragma unroll
      for (int i = 0; i < 2; ++i)
        #pragma unroll
        for (int j = 0; j < 4; ++j)
          Oacc[i][j] = __builtin_amdgcn_mfma_f32_16x16x32_bf16(pa[i], vb[j], Oacc[i][j], 0, 0, 0);
    }
  }

  // ---- epilogue: O/l -> bf16 hi/lo planes (feeds Wo split-GEMM) ----
  #pragma unroll
  for (int i = 0; i < 2; ++i) {
    float inv[4];
    #pragma unroll
    for (int r = 0; r < 4; ++r) inv[r] = 1.0f / l_i[i][r];
    #pragma unroll
    for (int j = 0; j < 4; ++j)
      #pragma unroll
      for (int r = 0; r < 4; ++r) {
        int row = q0 + wq + 16*i + 4*lq + r;
        float val = Oacc[i][j][r] * inv[r];
        unsigned short hv = f2bf(val);
        unsigned short lv = f2bf(val - bf2f(hv));
        size_t addr = hbase + (size_t)row * kD + 16*j + lr;
        oHi[addr] = hv;
        oLo[addr] = lv;
      }
  }
}

// ---------------------------------------------------------------------------
// Orchestration. Workspace byte layout (96 MiB):
//   x    [ 0,16)MB fp32
//   hHi  [16,24)MB   hLo [24,32)MB           (bf16 activation planes)
//   q    [32,40)MB  k [40,48)MB  v [48,56)MB (bf16, attention phase)
//   f    [32,64)MB  bf16 FFN plane (aliases q,k,v — dead by FFN)
//   Wbuf [80,96)MB  rotating weight hi/lo planes
// ---------------------------------------------------------------------------
extern "C" void kernel_launch(void* const* d_in, const int* in_sizes, int n_in,
                              void* d_out, int out_size, void* d_ws, size_t ws_size,
                              hipStream_t stream) {
  const int*   tokens = (const int*)d_in[0];
  const int*   mask   = (const int*)d_in[1];
  const float* emb    = (const float*)d_in[2];
  const float* pe     = (const float*)d_in[3];
  const float* Wq     = (const float*)d_in[4];
  const float* bq     = (const float*)d_in[5];
  const float* Wk     = (const float*)d_in[6];
  const float* bk     = (const float*)d_in[7];
  const float* Wv     = (const float*)d_in[8];
  const float* bv     = (const float*)d_in[9];
  const float* Wo     = (const float*)d_in[10];
  const float* bo     = (const float*)d_in[11];
  const float* w1     = (const float*)d_in[12];
  const float* b1     = (const float*)d_in[13];
  const float* w2     = (const float*)d_in[14];
  const float* b2     = (const float*)d_in[15];
  const float* ln_a   = (const float*)d_in[16];
  const float* ln_b   = (const float*)d_in[17];
  const float* fa     = (const float*)d_in[18];
  const float* fb     = (const float*)d_in[19];
  float* out = (float*)d_out;
  char*  ws  = (char*)d_ws;

  const int T = kB * kS;                       // 4096 rows
  constexpr size_t MB = 1024 * 1024;

  float*          x    = (float*)(ws);
  unsigned short* hHi  = (unsigned short*)(ws + 16 * MB);
  unsigned short* hLo  = (unsigned short*)(ws + 24 * MB);
  unsigned short* qb   = (unsigned short*)(ws + 32 * MB);
  unsigned short* kb   = (unsigned short*)(ws + 40 * MB);
  unsigned short* vb   = (unsigned short*)(ws + 48 * MB);
  unsigned short* fpln = (unsigned short*)(ws + 32 * MB);   // aliases q,k,v
  char*           Wbuf = ws + 80 * MB;

  dim3 blk(256);
  embed_kernel<<<T, blk, 0, stream>>>(tokens, emb, pe, x);

  for (int l = 0; l < kL; ++l) {
    const float* Wql = Wq + (size_t)l * kD * kD;
    const float* Wkl = Wk + (size_t)l * kD * kD;
    const float* Wvl = Wv + (size_t)l * kD * kD;
    const float* Wol = Wo + (size_t)l * kD * kD;
    const float* w1l = w1 + (size_t)l * kD * kF;
    const float* w2l = w2 + (size_t)l * kF * kD;

    unsigned short* sq_hi = (unsigned short*)(Wbuf + 0 * MB);
    unsigned short* sq_lo = (unsigned short*)(Wbuf + 2 * MB);
    unsigned short* sk_hi = (unsigned short*)(Wbuf + 4 * MB);
    unsigned short* sk_lo = (unsigned short*)(Wbuf + 6 * MB);
    unsigned short* sv_hi = (unsigned short*)(Wbuf + 8 * MB);
    unsigned short* sv_lo = (unsigned short*)(Wbuf + 10 * MB);
    unsigned short* so_hi = (unsigned short*)(Wbuf + 12 * MB);
    unsigned short* so_lo = (unsigned short*)(Wbuf + 14 * MB);
    wconv_kernel<<<dim3(kD/64, kD/64), blk, 0, stream>>>(Wql, sq_hi, sq_lo, kD, kD);
    wconv_kernel<<<dim3(kD/64, kD/64), blk, 0, stream>>>(Wkl, sk_hi, sk_lo, kD, kD);
    wconv_kernel<<<dim3(kD/64, kD/64), blk, 0, stream>>>(Wvl, sv_hi, sv_lo, kD, kD);
    wconv_kernel<<<dim3(kD/64, kD/64), blk, 0, stream>>>(Wol, so_hi, so_lo, kD, kD);

    // --- attention sublayer ---
    ln_split_kernel<<<T, blk, 0, stream>>>(x, ln_a + (size_t)l * 2 * kD,
                                           ln_b + (size_t)l * 2 * kD, hHi, hLo);
    mfma_gemm<3,2><<<dim3(kD/128, T/128), blk, 0, stream>>>(
        hHi, hLo, sq_hi, sq_lo, bq + (size_t)l * kD, nullptr, qb, T, kD, kD);
    mfma_gemm<3,2><<<dim3(kD/128, T/128), blk, 0, stream>>>(
        hHi, hLo, sk_hi, sk_lo, bk + (size_t)l * kD, nullptr, kb, T, kD, kD);
    mfma_gemm<3,2><<<dim3(kD/128, T/128), blk, 0, stream>>>(
        hHi, hLo, sv_hi, sv_lo, bv + (size_t)l * kD, nullptr, vb, T, kD, kD);
    attn_kernel<<<kB * kH * (kS / 128), blk, 0, stream>>>(qb, kb, vb, mask, hHi, hLo);
    mfma_gemm<3,0><<<dim3(kD/128, T/128), blk, 0, stream>>>(
        hHi, hLo, so_hi, so_lo, bo + (size_t)l * kD, x, x, T, kD, kD);

    // --- feed-forward sublayer ---
    ln_split_kernel<<<T, blk, 0, stream>>>(x, ln_a + (size_t)l * 2 * kD + kD,
                                           ln_b + (size_t)l * 2 * kD + kD, hHi, hLo);
    unsigned short* w1_hi = (unsigned short*)(Wbuf);
    unsigned short* w1_lo = (unsigned short*)(Wbuf + 8 * MB);
    wconv_kernel<<<dim3(kF/64, kD/64), blk, 0, stream>>>(w1l, w1_hi, w1_lo, kD, kF);
    mfma_gemm<3,1><<<dim3(kF/128, T/128), blk, 0, stream>>>(
        hHi, hLo, w1_hi, w1_lo, b1 + (size_t)l * kF, nullptr, fpln, T, kF, kD);
    unsigned short* w2_hi = (unsigned short*)(Wbuf);
    unsigned short* w2_lo = (unsigned short*)(Wbuf + 8 * MB);
    wconv_kernel<<<dim3(kD/64, kF/64), blk, 0, stream>>>(w2l, w2_hi, w2_lo, kF, kD);
    mfma_gemm<2,0><<<dim3(kD/128, T/128), blk, 0, stream>>>(
        fpln, nullptr, w2_hi, w2_lo, b2 + (size_t)l * kD, x, x, T, kD, kF);
  }

  ln_kernel<<<T, blk, 0, stream>>>(x, fa, fb, out);
}

// Round 6
// 1985.811 us; speedup vs baseline: 9.6800x; 2.0890x over previous
//
#include <hip/hip_runtime.h>
#include <math.h>
#include <stdint.h>

// Problem constants (match reference)
constexpr int kB = 2, kS = 2048, kD = 1024, kH = 16, kF = 4096, kL = 3;
constexpr int kDK = 64;
constexpr int kQKV = 3 * kD;            // fused QKV width 3072

typedef __attribute__((ext_vector_type(8))) short short8;
typedef __attribute__((ext_vector_type(4))) float floatx4;

// bf16 helpers (RNE pack, shift-unpack)
__device__ inline float bf2f(unsigned short u) {
  union { uint32_t i; float f; } v; v.i = (uint32_t)u << 16; return v.f;
}
__device__ inline unsigned short f2bf(float x) {
  union { float f; uint32_t i; } v; v.f = x;
  uint32_t r = v.i + 0x7fffu + ((v.i >> 16) & 1u);
  return (unsigned short)(r >> 16);
}

// async global->LDS DMA, 16B per lane; LDS dest = wave-uniform base + lane*16
__device__ inline void dma16(const void* g, void* l) {
  __builtin_amdgcn_global_load_lds(
      (const __attribute__((address_space(1))) unsigned int*)g,
      (__attribute__((address_space(3))) unsigned int*)l, 16, 0, 0);
}

// ---------------------------------------------------------------------------
// Embedding: x[b,s,:] = emb[tok]*sqrt(D) + pe[s,:]
// ---------------------------------------------------------------------------
__global__ __launch_bounds__(256) void embed_kernel(
    const int* __restrict__ tokens, const float* __restrict__ emb,
    const float* __restrict__ pe, float* __restrict__ x)
{
  int i = blockIdx.x;
  int s = i & (kS - 1);
  int tok = tokens[i];
  const float4* ep = (const float4*)(emb + (size_t)tok * kD);
  const float4* pp = (const float4*)(pe + (size_t)s * kD);
  float4* xp = (float4*)(x + (size_t)i * kD);
  int t = threadIdx.x;
  float4 e = ep[t], p = pp[t];
  xp[t] = make_float4(e.x*32.0f + p.x, e.y*32.0f + p.y,
                      e.z*32.0f + p.z, e.w*32.0f + p.w);
}

// ---------------------------------------------------------------------------
// LayerNorm (torch-style: Bessel std ddof=1, eps on std) -> fp32 out
// ---------------------------------------------------------------------------
__global__ __launch_bounds__(256) void ln_kernel(
    const float* __restrict__ x, const float* __restrict__ ga,
    const float* __restrict__ gb, float* __restrict__ out)
{
  int row = blockIdx.x;
  int t = threadIdx.x;
  int lane = t & 63, wid = t >> 6;
  const float4* xp = (const float4*)(x + (size_t)row * kD);
  float4 v = xp[t];
  float s = v.x + v.y + v.z + v.w;
  #pragma unroll
  for (int o = 32; o; o >>= 1) s += __shfl_xor(s, o);
  __shared__ float red[4];
  if (lane == 0) red[wid] = s;
  __syncthreads();
  float mean = (red[0] + red[1] + red[2] + red[3]) * (1.0f / 1024.0f);
  float4 d = make_float4(v.x - mean, v.y - mean, v.z - mean, v.w - mean);
  float ss = d.x*d.x + d.y*d.y + d.z*d.z + d.w*d.w;
  #pragma unroll
  for (int o = 32; o; o >>= 1) ss += __shfl_xor(ss, o);
  __syncthreads();
  if (lane == 0) red[wid] = ss;
  __syncthreads();
  float var = (red[0] + red[1] + red[2] + red[3]) * (1.0f / 1023.0f);
  float inv = 1.0f / (sqrtf(var) + 1e-6f);
  float4 a4 = ((const float4*)ga)[t];
  float4 b4 = ((const float4*)gb)[t];
  float4 o4;
  o4.x = a4.x * d.x * inv + b4.x;
  o4.y = a4.y * d.y * inv + b4.y;
  o4.z = a4.z * d.z * inv + b4.z;
  o4.w = a4.w * d.w * inv + b4.w;
  ((float4*)(out + (size_t)row * kD))[t] = o4;
}

// ---------------------------------------------------------------------------
// LayerNorm -> bf16 hi/lo planes (input to split-bf16 MFMA GEMMs)
// ---------------------------------------------------------------------------
__global__ __launch_bounds__(256) void ln_split_kernel(
    const float* __restrict__ x, const float* __restrict__ ga,
    const float* __restrict__ gb, unsigned short* __restrict__ hi,
    unsigned short* __restrict__ lo)
{
  int row = blockIdx.x;
  int t = threadIdx.x;
  int lane = t & 63, wid = t >> 6;
  const float4* xp = (const float4*)(x + (size_t)row * kD);
  float4 v = xp[t];
  float s = v.x + v.y + v.z + v.w;
  #pragma unroll
  for (int o = 32; o; o >>= 1) s += __shfl_xor(s, o);
  __shared__ float red[4];
  if (lane == 0) red[wid] = s;
  __syncthreads();
  float mean = (red[0] + red[1] + red[2] + red[3]) * (1.0f / 1024.0f);
  float4 d = make_float4(v.x - mean, v.y - mean, v.z - mean, v.w - mean);
  float ss = d.x*d.x + d.y*d.y + d.z*d.z + d.w*d.w;
  #pragma unroll
  for (int o = 32; o; o >>= 1) ss += __shfl_xor(ss, o);
  __syncthreads();
  if (lane == 0) red[wid] = ss;
  __syncthreads();
  float var = (red[0] + red[1] + red[2] + red[3]) * (1.0f / 1023.0f);
  float inv = 1.0f / (sqrtf(var) + 1e-6f);
  float4 a4 = ((const float4*)ga)[t];
  float4 b4 = ((const float4*)gb)[t];
  float o0 = a4.x * d.x * inv + b4.x;
  float o1 = a4.y * d.y * inv + b4.y;
  float o2 = a4.z * d.z * inv + b4.z;
  float o3 = a4.w * d.w * inv + b4.w;
  ushort4 h4, l4;
  h4.x = f2bf(o0); l4.x = f2bf(o0 - bf2f(h4.x));
  h4.y = f2bf(o1); l4.y = f2bf(o1 - bf2f(h4.y));
  h4.z = f2bf(o2); l4.z = f2bf(o2 - bf2f(h4.z));
  h4.w = f2bf(o3); l4.w = f2bf(o3 - bf2f(h4.w));
  *(ushort4*)&hi[(size_t)row * kD + 4*t] = h4;
  *(ushort4*)&lo[(size_t)row * kD + 4*t] = l4;
}

// ---------------------------------------------------------------------------
// Weight convert: W[K][N] fp32 -> transposed bf16 hi/lo planes Wt[N][K].
// ---------------------------------------------------------------------------
__global__ __launch_bounds__(256) void wconv_kernel(
    const float* __restrict__ W, unsigned short* __restrict__ hi,
    unsigned short* __restrict__ lo, int K, int N)
{
  __shared__ float tile[64][65];
  int n0 = blockIdx.x * 64, k0 = blockIdx.y * 64;
  int c = threadIdx.x & 63, r0 = threadIdx.x >> 6;
  #pragma unroll
  for (int p = 0; p < 16; ++p) {
    int r = r0 + 4 * p;
    tile[r][c] = W[(size_t)(k0 + r) * N + n0 + c];
  }
  __syncthreads();
  #pragma unroll
  for (int p = 0; p < 16; ++p) {
    int nn = r0 + 4 * p;
    float xv = tile[c][nn];                 // = W[k0+c][n0+nn]
    unsigned short h = f2bf(xv);
    size_t o = (size_t)(n0 + nn) * K + k0 + c;
    hi[o] = h;
    lo[o] = f2bf(xv - bf2f(h));
  }
}

// ---------------------------------------------------------------------------
// Split-bf16 MFMA GEMM v2.  A hi/lo [M][K] bf16; W hi/lo transposed [N][K].
// TERMS=3: Ahi*Whi + Ahi*Wlo + Alo*Whi.  TERMS=2: Ahi*(Whi+Wlo).
// 128x128 tile, BK=32, 4 waves (64x64, 4x4 mfma_16x16x32_bf16).
// Staging via global_load_lds width=16 (async DMA, no VGPR round-trip — R5's
// pf[] prefetch array spilled to scratch: 857MB of phantom HBM writes/disp).
// No LDS padding (DMA is lane-contiguous); instead chunk-XOR swizzle
// kq_lds = kq ^ ((row^(row>>2))&3), applied on the global address side ->
// frag ds_read_b128 hits 8 bank-groups x 2-way = conflict-free (m136).
// LDS 32KB (24KB TERMS=2); __launch_bounds__(256,3) -> 3 blocks/CU.
// OUTMODE 0: fp32 (+resid). 1: relu->bf16 plane. 2: bf16 plane.
// ---------------------------------------------------------------------------
template<int TERMS, int OUTMODE>
__global__ __launch_bounds__(256, 3) void mfma_gemm(
    const unsigned short* __restrict__ Ahi, const unsigned short* __restrict__ Alo,
    const unsigned short* __restrict__ Whi, const unsigned short* __restrict__ Wlo,
    const float* __restrict__ bias, const float* __restrict__ resid,
    void* __restrict__ out, int M, int N, int K)
{
  __shared__ unsigned short sAhi[128 * 32];
  __shared__ unsigned short sBhi[128 * 32];
  __shared__ unsigned short sBlo[128 * 32];
  __shared__ unsigned short sAlo[TERMS == 3 ? 128 * 32 : 64];

  int t = threadIdx.x;
  int lane = t & 63, wv = t >> 6;
  int wm = (wv >> 1) * 64, wn = (wv & 1) * 64;
  int lr = lane & 15, lq = lane >> 4;
  int m0 = blockIdx.y * 128, n0 = blockIdx.x * 128;

  // DMA lane mapping: wave-op W covers rows 16W..16W+15, lane l -> row
  // 16W+(l>>2), global chunk (l&3)^s(row), s = ((l>>2)^(l>>4))&3.
  int u = lane >> 2;
  int kq_g = (lane & 3) ^ ((u ^ (u >> 2)) & 3);
  // fragment-read swizzle: s depends only on row mod 16 (= lr)
  int swv = (lr ^ (lr >> 2)) & 3;

  floatx4 acc[4][4];
  #pragma unroll
  for (int i = 0; i < 4; ++i)
    #pragma unroll
    for (int j = 0; j < 4; ++j) acc[i][j] = (floatx4){0.f, 0.f, 0.f, 0.f};

  for (int k0 = 0; k0 < K; k0 += 32) {
    __syncthreads();                         // prev iter's frag readers done
    #pragma unroll
    for (int p = 0; p < 2; ++p) {
      int W = 2 * wv + p;
      size_t ga = (size_t)(m0 + 16 * W + u) * K + k0 + 8 * kq_g;
      size_t gb = (size_t)(n0 + 16 * W + u) * K + k0 + 8 * kq_g;
      dma16(&Ahi[ga], &sAhi[W * 512]);
      if (TERMS == 3) dma16(&Alo[ga], &sAlo[W * 512]);
      dma16(&Whi[gb], &sBhi[W * 512]);
      dma16(&Wlo[gb], &sBlo[W * 512]);
    }
    __syncthreads();                         // drains vmcnt -> DMA visible

    short8 ah[4], bh[4];
    #pragma unroll
    for (int i = 0; i < 4; ++i)
      ah[i] = *(const short8*)&sAhi[(wm + 16*i + lr) * 32 + 8 * (lq ^ swv)];
    #pragma unroll
    for (int j = 0; j < 4; ++j)
      bh[j] = *(const short8*)&sBhi[(wn + 16*j + lr) * 32 + 8 * (lq ^ swv)];
    #pragma unroll
    for (int i = 0; i < 4; ++i)
      #pragma unroll
      for (int j = 0; j < 4; ++j)
        acc[i][j] = __builtin_amdgcn_mfma_f32_16x16x32_bf16(ah[i], bh[j], acc[i][j], 0, 0, 0);

    short8 bl[4];
    #pragma unroll
    for (int j = 0; j < 4; ++j)
      bl[j] = *(const short8*)&sBlo[(wn + 16*j + lr) * 32 + 8 * (lq ^ swv)];
    #pragma unroll
    for (int i = 0; i < 4; ++i)
      #pragma unroll
      for (int j = 0; j < 4; ++j)
        acc[i][j] = __builtin_amdgcn_mfma_f32_16x16x32_bf16(ah[i], bl[j], acc[i][j], 0, 0, 0);

    if (TERMS == 3) {
      short8 al[4];
      #pragma unroll
      for (int i = 0; i < 4; ++i)
        al[i] = *(const short8*)&sAlo[(wm + 16*i + lr) * 32 + 8 * (lq ^ swv)];
      #pragma unroll
      for (int i = 0; i < 4; ++i)
        #pragma unroll
        for (int j = 0; j < 4; ++j)
          acc[i][j] = __builtin_amdgcn_mfma_f32_16x16x32_bf16(al[i], bh[j], acc[i][j], 0, 0, 0);
    }
  }

  // epilogue: C/D layout col=lane&15, row=(lane>>4)*4+reg
  #pragma unroll
  for (int i = 0; i < 4; ++i) {
    #pragma unroll
    for (int j = 0; j < 4; ++j) {
      int col = n0 + wn + 16*j + lr;
      float bv = bias[col];
      #pragma unroll
      for (int r = 0; r < 4; ++r) {
        int row = m0 + wm + 16*i + 4*lq + r;
        float val = acc[i][j][r] + bv;
        if (OUTMODE == 0) {
          if (resid) val += resid[(size_t)row * N + col];
          ((float*)out)[(size_t)row * N + col] = val;
        } else if (OUTMODE == 1) {
          ((unsigned short*)out)[(size_t)row * N + col] = f2bf(fmaxf(val, 0.f));
        } else {
          ((unsigned short*)out)[(size_t)row * N + col] = f2bf(val);
        }
      }
    }
  }
}

// ---------------------------------------------------------------------------
// MFMA flash attention (R5 design, + runtime row stride for fused-QKV input).
// ---------------------------------------------------------------------------
#define ASTR 72

__global__ __launch_bounds__(256) void attn_kernel(
    const unsigned short* __restrict__ Qg, const unsigned short* __restrict__ Kg,
    const unsigned short* __restrict__ Vg, const int* __restrict__ mask,
    unsigned short* __restrict__ oHi, unsigned short* __restrict__ oLo, int ldq)
{
  __shared__ unsigned short Qs[128 * ASTR];  // [q][d]
  __shared__ unsigned short Ks[64 * ASTR];   // [k][d]
  __shared__ unsigned short Vs[64 * ASTR];   // [d][k] (transposed)
  __shared__ unsigned short Ps[128 * ASTR];  // [q][k]

  int bi = blockIdx.x;
  int qt = bi & 15;
  int h  = (bi >> 4) & 15;
  int b  = bi >> 8;
  int q0 = qt * 128;
  int t = threadIdx.x;
  int lane = t & 63, wv = t >> 6;
  int lr = lane & 15, lq = lane >> 4;
  int wq = wv * 32;

  const size_t hin  = (size_t)b * kS * ldq + (size_t)h * kDK;   // q/k/v base
  const size_t hout = (size_t)b * kS * kD  + (size_t)h * kDK;   // output base

  #pragma unroll
  for (int p = 0; p < 4; ++p) {
    int c = t + 256 * p;
    int row = c >> 3, dq = c & 7;
    *(uint4*)&Qs[row * ASTR + 8 * dq] =
        *(const uint4*)&Qg[hin + (size_t)(q0 + row) * ldq + 8 * dq];
  }

  floatx4 Oacc[2][4];
  float m_i[2][4], l_i[2][4];
  #pragma unroll
  for (int i = 0; i < 2; ++i)
    #pragma unroll
    for (int r = 0; r < 4; ++r) {
      m_i[i][r] = -3.0e38f; l_i[i][r] = 0.0f;
    }
  #pragma unroll
  for (int i = 0; i < 2; ++i)
    #pragma unroll
    for (int j = 0; j < 4; ++j) Oacc[i][j] = (floatx4){0.f, 0.f, 0.f, 0.f};

  for (int k0 = 0; k0 < kS; k0 += 64) {
    __syncthreads();

    #pragma unroll
    for (int p = 0; p < 2; ++p) {
      int c = t + 256 * p;
      int row = c >> 3, dq = c & 7;
      size_t g = hin + (size_t)(k0 + row) * ldq + 8 * dq;
      *(uint4*)&Ks[row * ASTR + 8 * dq] = *(const uint4*)&Kg[g];
      uint4 vv = *(const uint4*)&Vg[g];
      const unsigned short* vs = (const unsigned short*)&vv;
      #pragma unroll
      for (int j = 0; j < 8; ++j)
        Vs[(8 * dq + j) * ASTR + row] = vs[j];
    }
    int mv[4];
    #pragma unroll
    for (int j = 0; j < 4; ++j) mv[j] = mask[b * kS + k0 + 16*j + lr];
    __syncthreads();

    floatx4 sac[2][4];
    #pragma unroll
    for (int i = 0; i < 2; ++i)
      #pragma unroll
      for (int j = 0; j < 4; ++j) sac[i][j] = (floatx4){0.f, 0.f, 0.f, 0.f};
    #pragma unroll
    for (int ks = 0; ks < 2; ++ks) {
      short8 af[2], bf[4];
      #pragma unroll
      for (int i = 0; i < 2; ++i)
        af[i] = *(const short8*)&Qs[(wq + 16*i + lr) * ASTR + 32*ks + 8*lq];
      #pragma unroll
      for (int j = 0; j < 4; ++j)
        bf[j] = *(const short8*)&Ks[(16*j + lr) * ASTR + 32*ks + 8*lq];
      #pragma unroll
      for (int i = 0; i < 2; ++i)
        #pragma unroll
        for (int j = 0; j < 4; ++j)
          sac[i][j] = __builtin_amdgcn_mfma_f32_16x16x32_bf16(af[i], bf[j], sac[i][j], 0, 0, 0);
    }

    #pragma unroll
    for (int i = 0; i < 2; ++i)
      #pragma unroll
      for (int j = 0; j < 4; ++j) {
        #pragma unroll
        for (int r = 0; r < 4; ++r) sac[i][j][r] *= 0.125f;
        if (mv[j] == 0)
          #pragma unroll
          for (int r = 0; r < 4; ++r) sac[i][j][r] = -1e9f;
      }

    float alf[2][4];
    #pragma unroll
    for (int i = 0; i < 2; ++i)
      #pragma unroll
      for (int r = 0; r < 4; ++r) {
        float mx = fmaxf(fmaxf(sac[i][0][r], sac[i][1][r]),
                         fmaxf(sac[i][2][r], sac[i][3][r]));
        #pragma unroll
        for (int o = 1; o < 16; o <<= 1) mx = fmaxf(mx, __shfl_xor(mx, o));
        float newm = fmaxf(m_i[i][r], mx);
        float rs = 0.0f;
        #pragma unroll
        for (int j = 0; j < 4; ++j) {
          float e = __expf(sac[i][j][r] - newm);
          sac[i][j][r] = e; rs += e;
        }
        #pragma unroll
        for (int o = 1; o < 16; o <<= 1) rs += __shfl_xor(rs, o);
        alf[i][r] = __expf(m_i[i][r] - newm);
        l_i[i][r] = l_i[i][r] * alf[i][r] + rs;
        m_i[i][r] = newm;
      }

    #pragma unroll
    for (int i = 0; i < 2; ++i)
      #pragma unroll
      for (int j = 0; j < 4; ++j)
        #pragma unroll
        for (int r = 0; r < 4; ++r)
          Ps[(wq + 16*i + 4*lq + r) * ASTR + 16*j + lr] = f2bf(sac[i][j][r]);

    #pragma unroll
    for (int i = 0; i < 2; ++i)
      #pragma unroll
      for (int j = 0; j < 4; ++j)
        #pragma unroll
        for (int r = 0; r < 4; ++r) Oacc[i][j][r] *= alf[i][r];

    #pragma unroll
    for (int ks = 0; ks < 2; ++ks) {
      short8 pa[2], vb[4];
      #pragma unroll
      for (int i = 0; i < 2; ++i)
        pa[i] = *(const short8*)&Ps[(wq + 16*i + lr) * ASTR + 32*ks + 8*lq];
      #pragma unroll
      for (int j = 0; j < 4; ++j)
        vb[j] = *(const short8*)&Vs[(16*j + lr) * ASTR + 32*ks + 8*lq];
      #pragma unroll
      for (int i = 0; i < 2; ++i)
        #pragma unroll
        for (int j = 0; j < 4; ++j)
          Oacc[i][j] = __builtin_amdgcn_mfma_f32_16x16x32_bf16(pa[i], vb[j], Oacc[i][j], 0, 0, 0);
    }
  }

  #pragma unroll
  for (int i = 0; i < 2; ++i) {
    float inv[4];
    #pragma unroll
    for (int r = 0; r < 4; ++r) inv[r] = 1.0f / l_i[i][r];
    #pragma unroll
    for (int j = 0; j < 4; ++j)
      #pragma unroll
      for (int r = 0; r < 4; ++r) {
        int row = q0 + wq + 16*i + 4*lq + r;
        float val = Oacc[i][j][r] * inv[r];
        unsigned short hv = f2bf(val);
        unsigned short lv = f2bf(val - bf2f(hv));
        size_t addr = hout + (size_t)row * kD + 16*j + lr;
        oHi[addr] = hv;
        oLo[addr] = lv;
      }
  }
}

// ---------------------------------------------------------------------------
// Orchestration. Workspace byte layout (<= 96 MiB):
//   x      [ 0,16) fp32
//   hHi    [16,24)   hLo [24,32)                 bf16 activation planes
//   qkv    [32,56)  bf16 [T][3072] fused QKV     (attention phase)
//   biasqkv[56,56+12KB) fp32[3072]               (attention phase)
//   fpln   [32,64)  bf16 FFN plane               (FFN phase, aliases qkv)
//   Wbuf   [64,96): qkv_hi[64,70) qkv_lo[70,76) so_hi[76,78) so_lo[78,80)
//                   ffn_hi[80,88) ffn_lo[88,96)  (w1 then w2, rotating)
// ---------------------------------------------------------------------------
extern "C" void kernel_launch(void* const* d_in, const int* in_sizes, int n_in,
                              void* d_out, int out_size, void* d_ws, size_t ws_size,
                              hipStream_t stream) {
  const int*   tokens = (const int*)d_in[0];
  const int*   mask   = (const int*)d_in[1];
  const float* emb    = (const float*)d_in[2];
  const float* pe     = (const float*)d_in[3];
  const float* Wq     = (const float*)d_in[4];
  const float* bq     = (const float*)d_in[5];
  const float* Wk     = (const float*)d_in[6];
  const float* bk     = (const float*)d_in[7];
  const float* Wv     = (const float*)d_in[8];
  const float* bv     = (const float*)d_in[9];
  const float* Wo     = (const float*)d_in[10];
  const float* bo     = (const float*)d_in[11];
  const float* w1     = (const float*)d_in[12];
  const float* b1     = (const float*)d_in[13];
  const float* w2     = (const float*)d_in[14];
  const float* b2     = (const float*)d_in[15];
  const float* ln_a   = (const float*)d_in[16];
  const float* ln_b   = (const float*)d_in[17];
  const float* fa     = (const float*)d_in[18];
  const float* fb     = (const float*)d_in[19];
  float* out = (float*)d_out;
  char*  ws  = (char*)d_ws;

  const int T = kB * kS;                       // 4096 rows
  constexpr size_t MB = 1024 * 1024;

  float*          x     = (float*)(ws);
  unsigned short* hHi   = (unsigned short*)(ws + 16 * MB);
  unsigned short* hLo   = (unsigned short*)(ws + 24 * MB);
  unsigned short* qkv   = (unsigned short*)(ws + 32 * MB);
  float*          bqkv  = (float*)(ws + 56 * MB);
  unsigned short* fpln  = (unsigned short*)(ws + 32 * MB);  // aliases qkv
  char*           Wbuf  = ws + 64 * MB;

  unsigned short* qkv_hi = (unsigned short*)(Wbuf);            // [3072][1024]
  unsigned short* qkv_lo = (unsigned short*)(Wbuf + 6 * MB);
  unsigned short* so_hi  = (unsigned short*)(Wbuf + 12 * MB);
  unsigned short* so_lo  = (unsigned short*)(Wbuf + 14 * MB);
  unsigned short* ffn_hi = (unsigned short*)(Wbuf + 16 * MB);
  unsigned short* ffn_lo = (unsigned short*)(Wbuf + 24 * MB);

  dim3 blk(256);
  embed_kernel<<<T, blk, 0, stream>>>(tokens, emb, pe, x);

  for (int l = 0; l < kL; ++l) {
    const float* Wql = Wq + (size_t)l * kD * kD;
    const float* Wkl = Wk + (size_t)l * kD * kD;
    const float* Wvl = Wv + (size_t)l * kD * kD;
    const float* Wol = Wo + (size_t)l * kD * kD;
    const float* w1l = w1 + (size_t)l * kD * kF;
    const float* w2l = w2 + (size_t)l * kF * kD;

    // fused QKV weight planes: rows 0..1023 = Wq^T, 1024.. = Wk^T, 2048.. = Wv^T
    wconv_kernel<<<dim3(kD/64, kD/64), blk, 0, stream>>>(
        Wql, qkv_hi,                 qkv_lo,                 kD, kD);
    wconv_kernel<<<dim3(kD/64, kD/64), blk, 0, stream>>>(
        Wkl, qkv_hi + (size_t)kD*kD, qkv_lo + (size_t)kD*kD, kD, kD);
    wconv_kernel<<<dim3(kD/64, kD/64), blk, 0, stream>>>(
        Wvl, qkv_hi + (size_t)2*kD*kD, qkv_lo + (size_t)2*kD*kD, kD, kD);
    wconv_kernel<<<dim3(kD/64, kD/64), blk, 0, stream>>>(Wol, so_hi, so_lo, kD, kD);
    hipMemcpyAsync(bqkv,          bq + (size_t)l*kD, kD*4, hipMemcpyDeviceToDevice, stream);
    hipMemcpyAsync(bqkv + kD,     bk + (size_t)l*kD, kD*4, hipMemcpyDeviceToDevice, stream);
    hipMemcpyAsync(bqkv + 2*kD,   bv + (size_t)l*kD, kD*4, hipMemcpyDeviceToDevice, stream);

    // --- attention sublayer ---
    ln_split_kernel<<<T, blk, 0, stream>>>(x, ln_a + (size_t)l * 2 * kD,
                                           ln_b + (size_t)l * 2 * kD, hHi, hLo);
    mfma_gemm<3,2><<<dim3(kQKV/128, T/128), blk, 0, stream>>>(
        hHi, hLo, qkv_hi, qkv_lo, bqkv, nullptr, qkv, T, kQKV, kD);
    attn_kernel<<<kB * kH * (kS / 128), blk, 0, stream>>>(
        qkv, qkv + kD, qkv + 2*kD, mask, hHi, hLo, kQKV);
    mfma_gemm<3,0><<<dim3(kD/128, T/128), blk, 0, stream>>>(
        hHi, hLo, so_hi, so_lo, bo + (size_t)l * kD, x, x, T, kD, kD);

    // --- feed-forward sublayer ---
    ln_split_kernel<<<T, blk, 0, stream>>>(x, ln_a + (size_t)l * 2 * kD + kD,
                                           ln_b + (size_t)l * 2 * kD + kD, hHi, hLo);
    wconv_kernel<<<dim3(kF/64, kD/64), blk, 0, stream>>>(w1l, ffn_hi, ffn_lo, kD, kF);
    mfma_gemm<3,1><<<dim3(kF/128, T/128), blk, 0, stream>>>(
        hHi, hLo, ffn_hi, ffn_lo, b1 + (size_t)l * kF, nullptr, fpln, T, kF, kD);
    wconv_kernel<<<dim3(kD/64, kF/64), blk, 0, stream>>>(w2l, ffn_hi, ffn_lo, kF, kD);
    mfma_gemm<2,0><<<dim3(kD/128, T/128), blk, 0, stream>>>(
        fpln, nullptr, ffn_hi, ffn_lo, b2 + (size_t)l * kD, x, x, T, kD, kF);
  }

  ln_kernel<<<T, blk, 0, stream>>>(x, fa, fb, out);
}